// Round 3
// baseline (1836.925 us; speedup 1.0000x reference)
//
#include <hip/hip_runtime.h>
#include <math.h>

// DyHeadBlock forward, fp32 correctness-first implementation.
// B=2, C=256, levels 64x64 / 32x32 / 16x16.

#define NB 2
#define NC 256

static __device__ __forceinline__ float hsig_(float x){
  return fminf(fmaxf(x + 3.f, 0.f), 6.f) * (1.f/6.f);
}

static __device__ __forceinline__ float blk_reduce(float v, float* buf){
  int t = threadIdx.x;
  buf[t] = v; __syncthreads();
  for(int s=128; s>0; s>>=1){
    if (t < s) buf[t] += buf[t+s];
    __syncthreads();
  }
  float r = buf[0];
  __syncthreads();
  return r;
}

// ---------------- offset/mask conv (27ch 3x3) ----------------
__global__ __launch_bounds__(256) void conv_off_kernel(
    const float* __restrict__ x, const float* __restrict__ w,
    const float* __restrict__ bias, float* __restrict__ off,
    float* __restrict__ mask, int H, int W){
  int N = H*W;
  int idx = blockIdx.x*256 + threadIdx.x;
  int total = NB*27*N;
  if (idx >= total) return;
  int hw = idx % N;
  int c  = (idx / N) % 27;
  int b  = idx / (27*N);
  int y = hw / W, x0 = hw % W;
  float acc = bias[c];
  const float* xb = x + (size_t)b*NC*N;
  for(int ky=0; ky<3; ++ky){
    int yy = y + ky - 1; if (yy < 0 || yy >= H) continue;
    for(int kx=0; kx<3; ++kx){
      int xx = x0 + kx - 1; if (xx < 0 || xx >= W) continue;
      const float* xp = xb + yy*W + xx;
      const float* wp = w + ((size_t)c*NC)*9 + ky*3 + kx;
      #pragma unroll 4
      for(int ci=0; ci<NC; ++ci)
        acc = fmaf(wp[ci*9], xp[(size_t)ci*N], acc);
    }
  }
  if (c < 18) off[((size_t)b*18 + c)*N + hw] = acc;
  else        mask[((size_t)b*9 + (c-18))*N + hw] = 1.f/(1.f + expf(-acc));
}

// ---------------- generic align-corners bilinear resize ----------------
__global__ __launch_bounds__(256) void resize_kernel(
    const float* __restrict__ in, float* __restrict__ out,
    int C, int H, int W, int Ho, int Wo){
  int No = Ho*Wo;
  int idx = blockIdx.x*256 + threadIdx.x;
  int total = NB*C*No;
  if (idx >= total) return;
  int xo = idx % Wo;
  int yo = (idx / Wo) % Ho;
  int bc = idx / No;
  float fy = (float)(H-1) / (float)(Ho-1);
  float fx = (float)(W-1) / (float)(Wo-1);
  float ys = yo * fy, xs = xo * fx;
  int y0 = (int)floorf(ys), x0i = (int)floorf(xs);
  int y1 = min(y0+1, H-1), x1 = min(x0i+1, W-1);
  float wy = ys - (float)y0, wx = xs - (float)x0i;
  const float* p = in + (size_t)bc*H*W;
  float v00 = p[y0*W+x0i], v01 = p[y0*W+x1];
  float v10 = p[y1*W+x0i], v11 = p[y1*W+x1];
  float r0 = v00*(1.f-wy) + v10*wy;
  float r1 = v01*(1.f-wy) + v11*wy;
  out[idx] = r0*(1.f-wx) + r1*wx;
}

// ---------------- deformable bilinear sampling into cols ----------------
// cols layout: [b][k][ci][hw]  (m = k*256+ci matches wt rows)
__global__ __launch_bounds__(256) void sample_kernel(
    const float* __restrict__ x, const float* __restrict__ off,
    const float* __restrict__ mask, float* __restrict__ cols,
    int Hi, int Wi, int Ho, int Wo, int stride){
  int N = Ho*Wo;
  int idx = blockIdx.x*256 + threadIdx.x;
  int total = NB*NC*N;
  if (idx >= total) return;
  int hw = idx % N;
  int ci = (idx / N) & (NC-1);
  int b  = idx / (NC*N);
  int yo = hw / Wo, xo = hw % Wo;
  const float* xp = x + ((size_t)b*NC + ci)*Hi*Wi;
  const float* ob = off + (size_t)b*18*N;
  const float* mb = mask + (size_t)b*9*N;
  float* cb = cols + ((size_t)b*9*NC + ci)*N + hw;
  float Hm1 = (float)(Hi-1), Wm1 = (float)(Wi-1);
  #pragma unroll
  for(int k=0; k<9; ++k){
    int ky = k/3, kx = k%3;
    float py = (float)(yo*stride - 1 + ky) + ob[(size_t)(2*k)*N + hw];
    float px = (float)(xo*stride - 1 + kx) + ob[(size_t)(2*k+1)*N + hw];
    float m  = mb[(size_t)k*N + hw];
    float y0f = floorf(py), x0f = floorf(px);
    float wy = py - y0f, wx = px - x0f;
    float val = 0.f;
    #pragma unroll
    for(int dy=0; dy<2; ++dy){
      float yf = y0f + (float)dy;
      float wyc = dy ? wy : (1.f - wy);
      bool vy = (yf >= 0.f) && (yf <= Hm1);
      int yi = min(max((int)yf, 0), Hi-1);
      #pragma unroll
      for(int dx=0; dx<2; ++dx){
        float xf = x0f + (float)dx;
        float wxc = dx ? wx : (1.f - wx);
        bool vx = (xf >= 0.f) && (xf <= Wm1);
        int xi = min(max((int)xf, 0), Wi-1);
        if (vy && vx) val = fmaf(wyc*wxc, xp[yi*Wi + xi], val);
      }
    }
    cb[(size_t)k*NC*N] = val * m;
  }
}

// ---------------- weight transpose: wt[k*256+ci][co] = w[co][ci][k] ----------------
__global__ __launch_bounds__(256) void wtrans_kernel(
    const float* __restrict__ w, float* __restrict__ wt){
  int idx = blockIdx.x*256 + threadIdx.x;
  if (idx >= 2304*256) return;
  int co = idx & 255;
  int m  = idx >> 8;       // k*256+ci
  int k  = m >> 8;
  int ci = m & 255;
  wt[(size_t)m*256 + co] = w[((size_t)co*256 + ci)*9 + k];
}

// ---------------- tiled fp32 GEMM: y[b][co][hw] = sum_m wt[m][co] * cols[b][m][hw] ----------------
__global__ __launch_bounds__(256) void gemm_kernel(
    const float* __restrict__ A,   // wt [2304][256]
    const float* __restrict__ Bc,  // cols [b][2304][N]
    float* __restrict__ Cmat,      // [b][256][N]
    int N){
  __shared__ float As[16][68];
  __shared__ float Bs[16][68];
  int tid = threadIdx.x;
  int tx = tid % 16, ty = tid / 16;
  int hw0 = blockIdx.x*64, co0 = blockIdx.y*64, b = blockIdx.z;
  const float* Bb = Bc + (size_t)b*2304*N;
  float acc[4][4] = {{0.f}};
  int lr = tid / 16, lc = (tid % 16)*4;
  for(int k0=0; k0<2304; k0+=16){
    *(float4*)&As[lr][lc] = *(const float4*)&A[(size_t)(k0+lr)*256 + co0 + lc];
    *(float4*)&Bs[lr][lc] = *(const float4*)&Bb[(size_t)(k0+lr)*N + hw0 + lc];
    __syncthreads();
    #pragma unroll
    for(int kk=0; kk<16; ++kk){
      float4 a = *(float4*)&As[kk][ty*4];
      float4 bv = *(float4*)&Bs[kk][tx*4];
      acc[0][0] = fmaf(a.x, bv.x, acc[0][0]); acc[0][1] = fmaf(a.x, bv.y, acc[0][1]);
      acc[0][2] = fmaf(a.x, bv.z, acc[0][2]); acc[0][3] = fmaf(a.x, bv.w, acc[0][3]);
      acc[1][0] = fmaf(a.y, bv.x, acc[1][0]); acc[1][1] = fmaf(a.y, bv.y, acc[1][1]);
      acc[1][2] = fmaf(a.y, bv.z, acc[1][2]); acc[1][3] = fmaf(a.y, bv.w, acc[1][3]);
      acc[2][0] = fmaf(a.z, bv.x, acc[2][0]); acc[2][1] = fmaf(a.z, bv.y, acc[2][1]);
      acc[2][2] = fmaf(a.z, bv.z, acc[2][2]); acc[2][3] = fmaf(a.z, bv.w, acc[2][3]);
      acc[3][0] = fmaf(a.w, bv.x, acc[3][0]); acc[3][1] = fmaf(a.w, bv.y, acc[3][1]);
      acc[3][2] = fmaf(a.w, bv.z, acc[3][2]); acc[3][3] = fmaf(a.w, bv.w, acc[3][3]);
    }
    __syncthreads();
  }
  #pragma unroll
  for(int i=0;i<4;++i){
    float4 v = make_float4(acc[i][0], acc[i][1], acc[i][2], acc[i][3]);
    *(float4*)&Cmat[(size_t)b*NC*N + (size_t)(co0+ty*4+i)*N + hw0 + tx*4] = v;
  }
}

// ---------------- GroupNorm (16 groups of 16 ch), in place ----------------
__global__ __launch_bounds__(256) void gn_kernel(
    float* __restrict__ f, const float* __restrict__ gamma,
    const float* __restrict__ beta, int N){
  __shared__ float buf1[256];
  __shared__ float buf2[256];
  int bg = blockIdx.x;           // 0..31
  int b = bg / 16, g = bg % 16;
  float* base = f + ((size_t)b*NC + g*16)*N;
  int cnt = 16*N;
  float s = 0.f, ss = 0.f;
  for(int i=threadIdx.x; i<cnt; i+=256){
    float v = base[i];
    s += v; ss = fmaf(v, v, ss);
  }
  float ts  = blk_reduce(s,  buf1);
  float tss = blk_reduce(ss, buf2);
  float mu  = ts / (float)cnt;
  float var = tss / (float)cnt - mu*mu;
  float rstd = rsqrtf(var + 1e-5f);
  for(int i=threadIdx.x; i<cnt; i+=256){
    int c = g*16 + i / N;
    base[i] = (base[i] - mu)*rstd*gamma[c] + beta[c];
  }
}

// ---------------- per-channel mean pooling ----------------
__global__ __launch_bounds__(256) void pool_kernel(
    const float* __restrict__ f, float* __restrict__ pooled, int N){
  __shared__ float buf[256];
  int bc = blockIdx.x;           // b*256 + c
  const float* p = f + (size_t)bc*N;
  float s = 0.f;
  for(int i=threadIdx.x; i<N; i+=256) s += p[i];
  float t = blk_reduce(s, buf);
  if (threadIdx.x == 0) pooled[bc] = t / (float)N;
}

// ---------------- scale attention scalar: s[b] = hsig(relu(pooled . wsc + bsc)) ----------------
__global__ __launch_bounds__(256) void attn_kernel(
    const float* __restrict__ pooled, const float* __restrict__ wsc,
    const float* __restrict__ bsc, float* __restrict__ scal){
  __shared__ float buf[256];
  int b = blockIdx.x;
  float v = pooled[b*NC + threadIdx.x] * wsc[threadIdx.x];
  float t = blk_reduce(v, buf);
  if (threadIdx.x == 0){
    float z = fmaxf(t + bsc[0], 0.f);
    scal[b] = hsig_(z);
  }
}

// ---------------- weighted combine: sum_feat = (sum feat_j * s_j[b]) / n ----------------
__global__ __launch_bounds__(256) void combine_kernel(
    const float* __restrict__ fm, const float* __restrict__ fl,
    const float* __restrict__ fh, const float* __restrict__ scal,
    float* __restrict__ outp, int N, float inv_n){
  int idx = blockIdx.x*256 + threadIdx.x;
  int total = NB*NC*N;
  if (idx >= total) return;
  int b = idx / (NC*N);
  float v = fm[idx] * scal[b];
  if (fl) v = fmaf(fl[idx], scal[2+b], v);
  if (fh) v = fmaf(fh[idx], scal[4+b], v);
  outp[idx] = v * inv_n;
}

// ---------------- DyReLU MLP: pooled(256) -> h(64) -> coef(1024) ----------------
__global__ __launch_bounds__(256) void dyrelu_mlp_kernel(
    const float* __restrict__ pooled,
    const float* __restrict__ w1, const float* __restrict__ b1,
    const float* __restrict__ w2, const float* __restrict__ b2,
    float* __restrict__ coef){
  __shared__ float pld[256];
  __shared__ float h[64];
  int b = blockIdx.x, t = threadIdx.x;
  pld[t] = pooled[b*NC + t];
  __syncthreads();
  if (t < 64){
    float a = b1[t];
    for(int c=0; c<256; ++c) a = fmaf(w1[t*256 + c], pld[c], a);
    h[t] = fmaxf(a, 0.f);
  }
  __syncthreads();
  for(int q=0; q<4; ++q){
    int o = q*256 + t;
    float a = b2[o];
    #pragma unroll 8
    for(int k=0; k<64; ++k) a = fmaf(w2[o*64 + k], h[k], a);
    coef[b*1024 + o] = hsig_(a) - 0.5f;
  }
}

// ---------------- DyReLU apply ----------------
__global__ __launch_bounds__(256) void dyrelu_apply_kernel(
    const float* __restrict__ sf, const float* __restrict__ coef,
    float* __restrict__ out, int N){
  int idx = blockIdx.x*256 + threadIdx.x;
  int total = NB*NC*N;
  if (idx >= total) return;
  int c = (idx / N) & (NC-1);
  int b = idx / (NC*N);
  const float* cf = coef + b*1024;
  float a1 = fmaf(cf[c], 2.f, 1.f);
  float bb1 = cf[256 + c];
  float a2 = cf[512 + c]*2.f;
  float bb2 = cf[768 + c];
  float v = sf[idx];
  out[idx] = fmaxf(fmaf(v, a1, bb1), fmaf(v, a2, bb2));
}

extern "C" void kernel_launch(void* const* d_in, const int* in_sizes, int n_in,
                              void* d_out, int out_size, void* d_ws, size_t ws_size,
                              hipStream_t stream){
  const float* x0      = (const float*)d_in[0];
  const float* x1      = (const float*)d_in[1];
  const float* x2      = (const float*)d_in[2];
  const float* w_off   = (const float*)d_in[3];
  const float* b_off   = (const float*)d_in[4];
  const float* w_mid   = (const float*)d_in[5];
  const float* g_mid   = (const float*)d_in[6];
  const float* bt_mid  = (const float*)d_in[7];
  const float* w_low   = (const float*)d_in[8];
  const float* g_low   = (const float*)d_in[9];
  const float* bt_low  = (const float*)d_in[10];
  const float* w_high  = (const float*)d_in[11];
  const float* g_high  = (const float*)d_in[12];
  const float* bt_high = (const float*)d_in[13];
  const float* w_scale = (const float*)d_in[14];
  const float* b_scale = (const float*)d_in[15];
  const float* w1      = (const float*)d_in[16];
  const float* b1      = (const float*)d_in[17];
  const float* w2      = (const float*)d_in[18];
  const float* b2      = (const float*)d_in[19];
  float* out = (float*)d_out;
  float* ws = (float*)d_ws;

  // workspace layout (floats); total ~29.9M floats (~120 MB)
  size_t o = 0;
  float* off0  = ws + o; o += (size_t)NB*18*4096;
  float* off1  = ws + o; o += (size_t)NB*18*1024;
  float* off2  = ws + o; o += (size_t)NB*18*256;
  float* mask0 = ws + o; o += (size_t)NB*9*4096;
  float* mask1 = ws + o; o += (size_t)NB*9*1024;
  float* mask2 = ws + o; o += (size_t)NB*9*256;
  float* offr  = ws + o; o += (size_t)NB*18*1024;
  float* maskr = ws + o; o += (size_t)NB*9*1024;
  float* wtm   = ws + o; o += (size_t)2304*256;
  float* wtl   = ws + o; o += (size_t)2304*256;
  float* wth   = ws + o; o += (size_t)2304*256;
  float* fmid  = ws + o; o += (size_t)NB*NC*4096;
  float* flow  = ws + o; o += (size_t)NB*NC*4096;
  float* fhis  = ws + o; o += (size_t)NB*NC*1024;
  float* fhi   = ws + o; o += (size_t)NB*NC*4096;
  float* sumf  = ws + o; o += (size_t)NB*NC*4096;
  float* plmid = ws + o; o += 512;
  float* pllow = ws + o; o += 512;
  float* plhi  = ws + o; o += 512;
  float* plsum = ws + o; o += 512;
  float* scal  = ws + o; o += 8;    // [mid b0,b1, low b0,b1, hi b0,b1]
  float* coef  = ws + o; o += (size_t)NB*1024;
  float* cols  = ws + o; o += (size_t)NB*9*NC*4096;
  (void)ws_size; (void)in_sizes; (void)n_in; (void)out_size;

  // weight transposes (cheap, every call)
  {
    int nthr = 2304*256;
    wtrans_kernel<<<(nthr+255)/256, 256, 0, stream>>>(w_mid, wtm);
    wtrans_kernel<<<(nthr+255)/256, 256, 0, stream>>>(w_low, wtl);
    wtrans_kernel<<<(nthr+255)/256, 256, 0, stream>>>(w_high, wth);
  }

  const int   sizes[3] = {64, 32, 16};
  const float* xs[3]   = {x0, x1, x2};
  float* OFF[3]  = {off0, off1, off2};
  float* MASK[3] = {mask0, mask1, mask2};
  const size_t outoff[3] = {0, (size_t)NB*NC*4096, (size_t)NB*NC*4096 + (size_t)NB*NC*1024};

  for(int l=0; l<3; ++l){
    int H = sizes[l], W = H, N = H*W;
    int totBCN = NB*NC*N;

    // offsets + masks for this level
    conv_off_kernel<<<(NB*27*N+255)/256, 256, 0, stream>>>(
        xs[l], w_off, b_off, OFF[l], MASK[l], H, W);

    // ---- mid ----
    sample_kernel<<<(totBCN+255)/256, 256, 0, stream>>>(
        xs[l], OFF[l], MASK[l], cols, H, W, H, W, 1);
    gemm_kernel<<<dim3(N/64, 4, NB), 256, 0, stream>>>(wtm, cols, fmid, N);
    gn_kernel<<<NB*16, 256, 0, stream>>>(fmid, g_mid, bt_mid, N);
    pool_kernel<<<NB*NC, 256, 0, stream>>>(fmid, plmid, N);
    attn_kernel<<<NB, 256, 0, stream>>>(plmid, w_scale, b_scale, scal + 0);

    int nf = 1;
    const float* flowp = nullptr;
    const float* fhip  = nullptr;

    // ---- low (stride-2 from previous, finer level) ----
    if (l > 0){
      int Hp = sizes[l-1];
      sample_kernel<<<(totBCN+255)/256, 256, 0, stream>>>(
          xs[l-1], OFF[l], MASK[l], cols, Hp, Hp, H, W, 2);
      gemm_kernel<<<dim3(N/64, 4, NB), 256, 0, stream>>>(wtl, cols, flow, N);
      gn_kernel<<<NB*16, 256, 0, stream>>>(flow, g_low, bt_low, N);
      pool_kernel<<<NB*NC, 256, 0, stream>>>(flow, pllow, N);
      attn_kernel<<<NB, 256, 0, stream>>>(pllow, w_scale, b_scale, scal + 2);
      nf++; flowp = flow;
    }

    // ---- high (next, coarser level; resized offsets; upsampled result) ----
    if (l < 2){
      int Ht = sizes[l+1], Nt = Ht*Ht;
      resize_kernel<<<(NB*18*Nt+255)/256, 256, 0, stream>>>(OFF[l], offr, 18, H, W, Ht, Ht);
      resize_kernel<<<(NB*9*Nt+255)/256, 256, 0, stream>>>(MASK[l], maskr, 9, H, W, Ht, Ht);
      sample_kernel<<<(NB*NC*Nt+255)/256, 256, 0, stream>>>(
          xs[l+1], offr, maskr, cols, Ht, Ht, Ht, Ht, 1);
      gemm_kernel<<<dim3(Nt/64, 4, NB), 256, 0, stream>>>(wth, cols, fhis, Nt);
      gn_kernel<<<NB*16, 256, 0, stream>>>(fhis, g_high, bt_high, Nt);
      resize_kernel<<<(totBCN+255)/256, 256, 0, stream>>>(fhis, fhi, NC, Ht, Ht, H, W);
      pool_kernel<<<NB*NC, 256, 0, stream>>>(fhi, plhi, N);
      attn_kernel<<<NB, 256, 0, stream>>>(plhi, w_scale, b_scale, scal + 4);
      nf++; fhip = fhi;
    }

    // ---- combine + DyReLU ----
    combine_kernel<<<(totBCN+255)/256, 256, 0, stream>>>(
        fmid, flowp, fhip, scal, sumf, N, 1.f/(float)nf);
    pool_kernel<<<NB*NC, 256, 0, stream>>>(sumf, plsum, N);
    dyrelu_mlp_kernel<<<NB, 256, 0, stream>>>(plsum, w1, b1, w2, b2, coef);
    dyrelu_apply_kernel<<<(totBCN+255)/256, 256, 0, stream>>>(
        sumf, coef, out + outoff[l], N);
  }
}

// Round 4
// 1186.534 us; speedup vs baseline: 1.5481x; 1.5481x over previous
//
#include <hip/hip_runtime.h>
#include <math.h>

// DyHeadBlock forward. B=2, C=256, levels 64x64 / 32x32 / 16x16.
// Round 4: bf16 MFMA GEMM (frag-ready global layouts, no LDS) + tiled conv_off.

#define NB 2
#define NC 256

typedef __attribute__((ext_vector_type(8))) short bf16x8;
typedef __attribute__((ext_vector_type(4))) float f32x4;

static __device__ __forceinline__ float hsig_(float x){
  return fminf(fmaxf(x + 3.f, 0.f), 6.f) * (1.f/6.f);
}

static __device__ __forceinline__ unsigned short bf16r(float f){
  unsigned int u = __float_as_uint(f);
  unsigned int r = (u + 0x7FFFu + ((u >> 16) & 1u)) >> 16;   // RTNE
  return (unsigned short)r;
}

static __device__ __forceinline__ float blk_reduce(float v, float* buf){
  int t = threadIdx.x;
  buf[t] = v; __syncthreads();
  for(int s=128; s>0; s>>=1){
    if (t < s) buf[t] += buf[t+s];
    __syncthreads();
  }
  float r = buf[0];
  __syncthreads();
  return r;
}

// ---------------- conv_off, tiled: 16x16 px tile, 32-ci chunk, partial sums ----------------
// grid: (tiles, 8, NB); partial[chunk][b][27][N]
__global__ __launch_bounds__(256) void conv_off_tiled(
    const float* __restrict__ x, const float* __restrict__ w,
    float* __restrict__ partial, int H, int W, int tilesx){
  __shared__ float hl[18][20];
  __shared__ float wl[32][9][28];
  int b = blockIdx.z, chunk = blockIdx.y;
  int ty0 = (blockIdx.x / tilesx) * 16, tx0 = (blockIdx.x % tilesx) * 16;
  int t = threadIdx.x;
  int ci0 = chunk * 32;
  int N = H * W;
  // stage weights for this ci-chunk: wl[ci][k][c]
  for (int s = t; s < 27*32*9; s += 256){
    int c = s / 288, rem = s % 288, ci = rem / 9, k = rem % 9;
    wl[ci][k][c] = w[((size_t)(c*NC + ci0 + ci))*9 + k];
  }
  float acc[27];
  #pragma unroll
  for (int c = 0; c < 27; ++c) acc[c] = 0.f;
  int ty = t >> 4, tx = t & 15;
  for (int ci = 0; ci < 32; ++ci){
    const float* xc = x + ((size_t)(b*NC + ci0 + ci))*N;
    __syncthreads();            // protect hl readers of previous iter (and wl stage on iter 0)
    for (int s = t; s < 324; s += 256){
      int hy = s / 18, hx = s % 18;
      int gy = ty0 + hy - 1, gx = tx0 + hx - 1;
      hl[hy][hx] = (gy >= 0 && gy < H && gx >= 0 && gx < W) ? xc[gy*W + gx] : 0.f;
    }
    __syncthreads();
    float xv[9];
    #pragma unroll
    for (int ky = 0; ky < 3; ++ky)
      #pragma unroll
      for (int kx = 0; kx < 3; ++kx)
        xv[ky*3+kx] = hl[ty+ky][tx+kx];
    #pragma unroll
    for (int k = 0; k < 9; ++k){
      float xk = xv[k];
      #pragma unroll
      for (int c4 = 0; c4 < 6; ++c4){
        float4 wv = *(float4*)&wl[ci][k][c4*4];
        acc[c4*4+0] = fmaf(wv.x, xk, acc[c4*4+0]);
        acc[c4*4+1] = fmaf(wv.y, xk, acc[c4*4+1]);
        acc[c4*4+2] = fmaf(wv.z, xk, acc[c4*4+2]);
        acc[c4*4+3] = fmaf(wv.w, xk, acc[c4*4+3]);
      }
      acc[24] = fmaf(wl[ci][k][24], xk, acc[24]);
      acc[25] = fmaf(wl[ci][k][25], xk, acc[25]);
      acc[26] = fmaf(wl[ci][k][26], xk, acc[26]);
    }
  }
  int hw = (ty0 + ty)*W + (tx0 + tx);
  float* pp = partial + ((size_t)(chunk*NB + b)*27)*N + hw;
  #pragma unroll
  for (int c = 0; c < 27; ++c) pp[(size_t)c*N] = acc[c];
}

// reduce 8 partials + bias -> off / sigmoid mask
__global__ __launch_bounds__(256) void conv_reduce(
    const float* __restrict__ partial, const float* __restrict__ bias,
    float* __restrict__ off, float* __restrict__ mask, int N){
  int idx = blockIdx.x*256 + threadIdx.x;
  int total = NB*27*N;
  if (idx >= total) return;
  int hw = idx % N;
  int c  = (idx / N) % 27;
  int b  = idx / (27*N);
  float s = bias[c];
  #pragma unroll
  for (int p = 0; p < 8; ++p)
    s += partial[((size_t)(p*NB + b)*27 + c)*N + hw];
  if (c < 18) off[((size_t)b*18 + c)*N + hw] = s;
  else        mask[((size_t)b*9 + (c-18))*N + hw] = 1.f/(1.f + expf(-s));
}

// ---------------- generic align-corners bilinear resize ----------------
__global__ __launch_bounds__(256) void resize_kernel(
    const float* __restrict__ in, float* __restrict__ out,
    int C, int H, int W, int Ho, int Wo){
  int No = Ho*Wo;
  int idx = blockIdx.x*256 + threadIdx.x;
  int total = NB*C*No;
  if (idx >= total) return;
  int xo = idx % Wo;
  int yo = (idx / Wo) % Ho;
  int bc = idx / No;
  float fy = (float)(H-1) / (float)(Ho-1);
  float fx = (float)(W-1) / (float)(Wo-1);
  float ys = yo * fy, xs = xo * fx;
  int y0 = (int)floorf(ys), x0i = (int)floorf(xs);
  int y1 = min(y0+1, H-1), x1 = min(x0i+1, W-1);
  float wy = ys - (float)y0, wx = xs - (float)x0i;
  const float* p = in + (size_t)bc*H*W;
  float v00 = p[y0*W+x0i], v01 = p[y0*W+x1];
  float v10 = p[y1*W+x0i], v11 = p[y1*W+x1];
  float r0 = v00*(1.f-wy) + v10*wy;
  float r1 = v01*(1.f-wy) + v11*wy;
  out[idx] = r0*(1.f-wx) + r1*wx;
}

// ---------------- deformable sampling -> colsT[b][m/8][hw][m%8] bf16 ----------------
// m = kp*256 + ci ; thread = (b, c8=ci/8, hw); writes 9 x 16B dense stores.
__global__ __launch_bounds__(256) void sample_t_kernel(
    const float* __restrict__ x, const float* __restrict__ off,
    const float* __restrict__ mask, unsigned short* __restrict__ colsT,
    int Hi, int Wi, int Ho, int Wo, int stride){
  int N = Ho*Wo;
  int idx = blockIdx.x*256 + threadIdx.x;
  int total = NB*32*N;
  if (idx >= total) return;
  int hw = idx % N;
  int c8 = (idx / N) & 31;
  int b  = idx / (32*N);
  int yo = hw / Wo, xo = hw % Wo;
  int HiWi = Hi*Wi;
  const float* xb = x + (size_t)(b*NC + c8*8)*HiWi;
  const float* ob = off + (size_t)b*18*N;
  const float* mb = mask + (size_t)b*9*N;
  unsigned short* cb = colsT + (size_t)b*288*N*8;
  float Hm1 = (float)(Hi-1), Wm1 = (float)(Wi-1);
  #pragma unroll
  for (int kp = 0; kp < 9; ++kp){
    int ky = kp/3, kx = kp%3;
    float py = (float)(yo*stride - 1 + ky) + ob[(size_t)(2*kp)*N + hw];
    float px = (float)(xo*stride - 1 + kx) + ob[(size_t)(2*kp+1)*N + hw];
    float m  = mb[(size_t)kp*N + hw];
    float y0f = floorf(py), x0f = floorf(px);
    float wy = py - y0f, wx = px - x0f;
    bool vy0 = (y0f >= 0.f)    && (y0f <= Hm1);
    bool vy1 = (y0f+1.f >= 0.f)&& (y0f+1.f <= Hm1);
    bool vx0 = (x0f >= 0.f)    && (x0f <= Wm1);
    bool vx1 = (x0f+1.f >= 0.f)&& (x0f+1.f <= Wm1);
    int y0i = min(max((int)y0f, 0), Hi-1);
    int y1i = min(max((int)y0f + 1, 0), Hi-1);
    int x0i = min(max((int)x0f, 0), Wi-1);
    int x1i = min(max((int)x0f + 1, 0), Wi-1);
    float w00 = (1.f-wy)*(1.f-wx) * (vy0 && vx0 ? 1.f : 0.f);
    float w01 = (1.f-wy)*wx       * (vy0 && vx1 ? 1.f : 0.f);
    float w10 = wy*(1.f-wx)       * (vy1 && vx0 ? 1.f : 0.f);
    float w11 = wy*wx             * (vy1 && vx1 ? 1.f : 0.f);
    int i00 = y0i*Wi + x0i, i01 = y0i*Wi + x1i;
    int i10 = y1i*Wi + x0i, i11 = y1i*Wi + x1i;
    unsigned int ou[4];
    #pragma unroll
    for (int p = 0; p < 4; ++p){
      const float* xp0 = xb + (size_t)(2*p)*HiWi;
      const float* xp1 = xb + (size_t)(2*p+1)*HiWi;
      float v0 = (w00*xp0[i00] + w01*xp0[i01] + w10*xp0[i10] + w11*xp0[i11]) * m;
      float v1 = (w00*xp1[i00] + w01*xp1[i01] + w10*xp1[i10] + w11*xp1[i11]) * m;
      ou[p] = (unsigned int)bf16r(v0) | ((unsigned int)bf16r(v1) << 16);
    }
    int chunk = kp*32 + c8;
    *(uint4*)(cb + ((size_t)chunk*N + hw)*8) =
        make_uint4(ou[0], ou[1], ou[2], ou[3]);
  }
}

// ---------------- weight re-tile: At[m/8][co][m%8] bf16, m = kp*256+ci ----------------
__global__ __launch_bounds__(256) void wtrans_t_kernel(
    const float* __restrict__ w, unsigned short* __restrict__ At){
  int j = blockIdx.x*256 + threadIdx.x;
  if (j >= 2304*256) return;
  int e = j & 7, co = (j >> 3) & 255, chunk = j >> 11;
  int kp = chunk >> 5, ci = (chunk & 31)*8 + e;
  At[j] = bf16r(w[((size_t)(co*NC + ci))*9 + kp]);
}

// ---------------- MFMA GEMM: C[b][co][hw] = sum_m At[m][co] * colsT[b][m][hw] ----------------
// block: 64 hw x 256 co, 4 waves (each 64co x 64hw), no LDS; frag-ready layouts.
__global__ __launch_bounds__(256) void gemm_t_kernel(
    const unsigned short* __restrict__ At,
    const unsigned short* __restrict__ colsT,
    float* __restrict__ C, int N){
  int b = blockIdx.z;
  int hw0 = blockIdx.x * 64;
  int tid = threadIdx.x;
  int wv = tid >> 6, l = tid & 63;
  int cobase = wv * 64;
  int lr = l & 15, lg = l >> 4;
  const unsigned short* Bb = colsT + (size_t)b*288*N*8;
  f32x4 acc[4][4];
  #pragma unroll
  for (int mi = 0; mi < 4; ++mi)
    #pragma unroll
    for (int ni = 0; ni < 4; ++ni)
      acc[mi][ni] = (f32x4){0.f, 0.f, 0.f, 0.f};
  for (int kc = 0; kc < 288; kc += 4){
    bf16x8 a[4], bfr[4];
    #pragma unroll
    for (int mi = 0; mi < 4; ++mi)
      a[mi] = *(const bf16x8*)(At + ((size_t)(kc+lg)*256 + cobase + mi*16 + lr)*8);
    #pragma unroll
    for (int ni = 0; ni < 4; ++ni)
      bfr[ni] = *(const bf16x8*)(Bb + ((size_t)(kc+lg)*N + hw0 + ni*16 + lr)*8);
    #pragma unroll
    for (int mi = 0; mi < 4; ++mi)
      #pragma unroll
      for (int ni = 0; ni < 4; ++ni)
        acc[mi][ni] = __builtin_amdgcn_mfma_f32_16x16x32_bf16(a[mi], bfr[ni], acc[mi][ni], 0, 0, 0);
  }
  #pragma unroll
  for (int mi = 0; mi < 4; ++mi)
    #pragma unroll
    for (int ni = 0; ni < 4; ++ni)
      #pragma unroll
      for (int r = 0; r < 4; ++r){
        int row = cobase + mi*16 + lg*4 + r;
        int col = hw0 + ni*16 + lr;
        C[((size_t)b*NC + row)*N + col] = acc[mi][ni][r];
      }
}

// ---------------- GroupNorm (16 groups of 16 ch), in place ----------------
__global__ __launch_bounds__(256) void gn_kernel(
    float* __restrict__ f, const float* __restrict__ gamma,
    const float* __restrict__ beta, int N){
  __shared__ float buf1[256];
  __shared__ float buf2[256];
  int bg = blockIdx.x;
  int b = bg / 16, g = bg % 16;
  float* base = f + ((size_t)b*NC + g*16)*N;
  int cnt = 16*N;
  float s = 0.f, ss = 0.f;
  for(int i=threadIdx.x; i<cnt; i+=256){
    float v = base[i];
    s += v; ss = fmaf(v, v, ss);
  }
  float ts  = blk_reduce(s,  buf1);
  float tss = blk_reduce(ss, buf2);
  float mu  = ts / (float)cnt;
  float var = tss / (float)cnt - mu*mu;
  float rstd = rsqrtf(var + 1e-5f);
  for(int i=threadIdx.x; i<cnt; i+=256){
    int c = g*16 + i / N;
    base[i] = (base[i] - mu)*rstd*gamma[c] + beta[c];
  }
}

// ---------------- per-channel mean pooling ----------------
__global__ __launch_bounds__(256) void pool_kernel(
    const float* __restrict__ f, float* __restrict__ pooled, int N){
  __shared__ float buf[256];
  int bc = blockIdx.x;
  const float* p = f + (size_t)bc*N;
  float s = 0.f;
  for(int i=threadIdx.x; i<N; i+=256) s += p[i];
  float t = blk_reduce(s, buf);
  if (threadIdx.x == 0) pooled[bc] = t / (float)N;
}

// ---------------- scale attention scalar ----------------
__global__ __launch_bounds__(256) void attn_kernel(
    const float* __restrict__ pooled, const float* __restrict__ wsc,
    const float* __restrict__ bsc, float* __restrict__ scal){
  __shared__ float buf[256];
  int b = blockIdx.x;
  float v = pooled[b*NC + threadIdx.x] * wsc[threadIdx.x];
  float t = blk_reduce(v, buf);
  if (threadIdx.x == 0){
    float z = fmaxf(t + bsc[0], 0.f);
    scal[b] = hsig_(z);
  }
}

// ---------------- weighted combine ----------------
__global__ __launch_bounds__(256) void combine_kernel(
    const float* __restrict__ fm, const float* __restrict__ fl,
    const float* __restrict__ fh, const float* __restrict__ scal,
    float* __restrict__ outp, int N, float inv_n){
  int idx = blockIdx.x*256 + threadIdx.x;
  int total = NB*NC*N;
  if (idx >= total) return;
  int b = idx / (NC*N);
  float v = fm[idx] * scal[b];
  if (fl) v = fmaf(fl[idx], scal[2+b], v);
  if (fh) v = fmaf(fh[idx], scal[4+b], v);
  outp[idx] = v * inv_n;
}

// ---------------- DyReLU MLP ----------------
__global__ __launch_bounds__(256) void dyrelu_mlp_kernel(
    const float* __restrict__ pooled,
    const float* __restrict__ w1, const float* __restrict__ b1,
    const float* __restrict__ w2, const float* __restrict__ b2,
    float* __restrict__ coef){
  __shared__ float pld[256];
  __shared__ float h[64];
  int b = blockIdx.x, t = threadIdx.x;
  pld[t] = pooled[b*NC + t];
  __syncthreads();
  if (t < 64){
    float a = b1[t];
    for(int c=0; c<256; ++c) a = fmaf(w1[t*256 + c], pld[c], a);
    h[t] = fmaxf(a, 0.f);
  }
  __syncthreads();
  for(int q=0; q<4; ++q){
    int o = q*256 + t;
    float a = b2[o];
    #pragma unroll 8
    for(int k=0; k<64; ++k) a = fmaf(w2[o*64 + k], h[k], a);
    coef[b*1024 + o] = hsig_(a) - 0.5f;
  }
}

// ---------------- DyReLU apply ----------------
__global__ __launch_bounds__(256) void dyrelu_apply_kernel(
    const float* __restrict__ sf, const float* __restrict__ coef,
    float* __restrict__ out, int N){
  int idx = blockIdx.x*256 + threadIdx.x;
  int total = NB*NC*N;
  if (idx >= total) return;
  int c = (idx / N) & (NC-1);
  int b = idx / (NC*N);
  const float* cf = coef + b*1024;
  float a1 = fmaf(cf[c], 2.f, 1.f);
  float bb1 = cf[256 + c];
  float a2 = cf[512 + c]*2.f;
  float bb2 = cf[768 + c];
  float v = sf[idx];
  out[idx] = fmaxf(fmaf(v, a1, bb1), fmaf(v, a2, bb2));
}

extern "C" void kernel_launch(void* const* d_in, const int* in_sizes, int n_in,
                              void* d_out, int out_size, void* d_ws, size_t ws_size,
                              hipStream_t stream){
  const float* x0      = (const float*)d_in[0];
  const float* x1      = (const float*)d_in[1];
  const float* x2      = (const float*)d_in[2];
  const float* w_off   = (const float*)d_in[3];
  const float* b_off   = (const float*)d_in[4];
  const float* w_mid   = (const float*)d_in[5];
  const float* g_mid   = (const float*)d_in[6];
  const float* bt_mid  = (const float*)d_in[7];
  const float* w_low   = (const float*)d_in[8];
  const float* g_low   = (const float*)d_in[9];
  const float* bt_low  = (const float*)d_in[10];
  const float* w_high  = (const float*)d_in[11];
  const float* g_high  = (const float*)d_in[12];
  const float* bt_high = (const float*)d_in[13];
  const float* w_scale = (const float*)d_in[14];
  const float* b_scale = (const float*)d_in[15];
  const float* w1      = (const float*)d_in[16];
  const float* b1      = (const float*)d_in[17];
  const float* w2      = (const float*)d_in[18];
  const float* b2      = (const float*)d_in[19];
  float* out = (float*)d_out;

  // byte-based workspace carve, 256B aligned
  char* wp_ = (char*)d_ws;
  auto alloc = [&](size_t bytes) -> char* {
    char* r = wp_;
    wp_ += (bytes + 255) & ~(size_t)255;
    return r;
  };
  float* off0  = (float*)alloc((size_t)NB*18*4096*4);
  float* off1  = (float*)alloc((size_t)NB*18*1024*4);
  float* off2  = (float*)alloc((size_t)NB*18*256*4);
  float* mask0 = (float*)alloc((size_t)NB*9*4096*4);
  float* mask1 = (float*)alloc((size_t)NB*9*1024*4);
  float* mask2 = (float*)alloc((size_t)NB*9*256*4);
  float* offr  = (float*)alloc((size_t)NB*18*1024*4);
  float* maskr = (float*)alloc((size_t)NB*9*1024*4);
  float* partial = (float*)alloc((size_t)8*NB*27*4096*4);
  unsigned short* Atm = (unsigned short*)alloc((size_t)2304*256*2);
  unsigned short* Atl = (unsigned short*)alloc((size_t)2304*256*2);
  unsigned short* Ath = (unsigned short*)alloc((size_t)2304*256*2);
  unsigned short* colsT = (unsigned short*)alloc((size_t)NB*288*4096*8*2);
  float* fmid  = (float*)alloc((size_t)NB*NC*4096*4);
  float* flow  = (float*)alloc((size_t)NB*NC*4096*4);
  float* fhis  = (float*)alloc((size_t)NB*NC*1024*4);
  float* fhi   = (float*)alloc((size_t)NB*NC*4096*4);
  float* sumf  = (float*)alloc((size_t)NB*NC*4096*4);
  float* plmid = (float*)alloc(512*4);
  float* pllow = (float*)alloc(512*4);
  float* plhi  = (float*)alloc(512*4);
  float* plsum = (float*)alloc(512*4);
  float* scal  = (float*)alloc(8*4);
  float* coef  = (float*)alloc((size_t)NB*1024*4);
  (void)ws_size; (void)in_sizes; (void)n_in; (void)out_size;

  // weight re-tiles (bf16, frag-ready)
  wtrans_t_kernel<<<2304, 256, 0, stream>>>(w_mid, Atm);
  wtrans_t_kernel<<<2304, 256, 0, stream>>>(w_low, Atl);
  wtrans_t_kernel<<<2304, 256, 0, stream>>>(w_high, Ath);

  const int   sizes[3] = {64, 32, 16};
  const float* xs[3]   = {x0, x1, x2};
  float* OFF[3]  = {off0, off1, off2};
  float* MASK[3] = {mask0, mask1, mask2};
  const size_t outoff[3] = {0, (size_t)NB*NC*4096, (size_t)NB*NC*4096 + (size_t)NB*NC*1024};

  for(int l=0; l<3; ++l){
    int H = sizes[l], W = H, N = H*W;
    int totBCN = NB*NC*N;
    int tilesx = H/16;

    conv_off_tiled<<<dim3(tilesx*tilesx, 8, NB), 256, 0, stream>>>(
        xs[l], w_off, partial, H, W, tilesx);
    conv_reduce<<<(NB*27*N+255)/256, 256, 0, stream>>>(
        partial, b_off, OFF[l], MASK[l], N);

    // ---- mid ----
    sample_t_kernel<<<(NB*32*N)/256, 256, 0, stream>>>(
        xs[l], OFF[l], MASK[l], colsT, H, W, H, W, 1);
    gemm_t_kernel<<<dim3(N/64, 1, NB), 256, 0, stream>>>(Atm, colsT, fmid, N);
    gn_kernel<<<NB*16, 256, 0, stream>>>(fmid, g_mid, bt_mid, N);
    pool_kernel<<<NB*NC, 256, 0, stream>>>(fmid, plmid, N);
    attn_kernel<<<NB, 256, 0, stream>>>(plmid, w_scale, b_scale, scal + 0);

    int nf = 1;
    const float* flowp = nullptr;
    const float* fhip  = nullptr;

    // ---- low (stride-2 from previous, finer level) ----
    if (l > 0){
      int Hp = sizes[l-1];
      sample_t_kernel<<<(NB*32*N)/256, 256, 0, stream>>>(
          xs[l-1], OFF[l], MASK[l], colsT, Hp, Hp, H, W, 2);
      gemm_t_kernel<<<dim3(N/64, 1, NB), 256, 0, stream>>>(Atl, colsT, flow, N);
      gn_kernel<<<NB*16, 256, 0, stream>>>(flow, g_low, bt_low, N);
      pool_kernel<<<NB*NC, 256, 0, stream>>>(flow, pllow, N);
      attn_kernel<<<NB, 256, 0, stream>>>(pllow, w_scale, b_scale, scal + 2);
      nf++; flowp = flow;
    }

    // ---- high (next, coarser level) ----
    if (l < 2){
      int Ht = sizes[l+1], Nt = Ht*Ht;
      resize_kernel<<<(NB*18*Nt+255)/256, 256, 0, stream>>>(OFF[l], offr, 18, H, W, Ht, Ht);
      resize_kernel<<<(NB*9*Nt+255)/256, 256, 0, stream>>>(MASK[l], maskr, 9, H, W, Ht, Ht);
      sample_t_kernel<<<(NB*32*Nt)/256, 256, 0, stream>>>(
          xs[l+1], offr, maskr, colsT, Ht, Ht, Ht, Ht, 1);
      gemm_t_kernel<<<dim3(Nt/64, 1, NB), 256, 0, stream>>>(Ath, colsT, fhis, Nt);
      gn_kernel<<<NB*16, 256, 0, stream>>>(fhis, g_high, bt_high, Nt);
      resize_kernel<<<(totBCN+255)/256, 256, 0, stream>>>(fhis, fhi, NC, Ht, Ht, H, W);
      pool_kernel<<<NB*NC, 256, 0, stream>>>(fhi, plhi, N);
      attn_kernel<<<NB, 256, 0, stream>>>(plhi, w_scale, b_scale, scal + 4);
      nf++; fhip = fhi;
    }

    // ---- combine + DyReLU ----
    combine_kernel<<<(totBCN+255)/256, 256, 0, stream>>>(
        fmid, flowp, fhip, scal, sumf, N, 1.f/(float)nf);
    pool_kernel<<<NB*NC, 256, 0, stream>>>(sumf, plsum, N);
    dyrelu_mlp_kernel<<<NB, 256, 0, stream>>>(plsum, w1, b1, w2, b2, coef);
    dyrelu_apply_kernel<<<(totBCN+255)/256, 256, 0, stream>>>(
        sumf, coef, out + outoff[l], N);
  }
}

// Round 6
// 1059.162 us; speedup vs baseline: 1.7343x; 1.1203x over previous
//
#include <hip/hip_runtime.h>
#include <math.h>

// DyHeadBlock forward. B=2, C=256, levels 64x64 / 32x32 / 16x16.
// Round 5: GN stats fused into GEMM epilogue; elementwise GN-apply with fused
// channel pooling; pools fused into resize/combine. Kills the 32-block GN wall.

#define NB 2
#define NC 256

typedef __attribute__((ext_vector_type(8))) short bf16x8;
typedef __attribute__((ext_vector_type(4))) float f32x4;

static __device__ __forceinline__ float hsig_(float x){
  return fminf(fmaxf(x + 3.f, 0.f), 6.f) * (1.f/6.f);
}

static __device__ __forceinline__ unsigned short bf16r(float f){
  unsigned int u = __float_as_uint(f);
  unsigned int r = (u + 0x7FFFu + ((u >> 16) & 1u)) >> 16;   // RTNE
  return (unsigned short)r;
}

static __device__ __forceinline__ float blk_reduce(float v, float* buf){
  int t = threadIdx.x;
  buf[t] = v; __syncthreads();
  for(int s=128; s>0; s>>=1){
    if (t < s) buf[t] += buf[t+s];
    __syncthreads();
  }
  float r = buf[0];
  __syncthreads();
  return r;
}

// ---------------- zero small stats/pool region ----------------
__global__ __launch_bounds__(256) void zero_kernel(float* __restrict__ p, int n){
  int i = blockIdx.x*256 + threadIdx.x;
  if (i < n) p[i] = 0.f;
}

// ---------------- conv_off, tiled: 16x16 px tile, 32-ci chunk, partial sums ----------------
__global__ __launch_bounds__(256) void conv_off_tiled(
    const float* __restrict__ x, const float* __restrict__ w,
    float* __restrict__ partial, int H, int W, int tilesx){
  __shared__ float hl[18][20];
  __shared__ float wl[32][9][28];
  int b = blockIdx.z, chunk = blockIdx.y;
  int ty0 = (blockIdx.x / tilesx) * 16, tx0 = (blockIdx.x % tilesx) * 16;
  int t = threadIdx.x;
  int ci0 = chunk * 32;
  int N = H * W;
  for (int s = t; s < 27*32*9; s += 256){
    int c = s / 288, rem = s % 288, ci = rem / 9, k = rem % 9;
    wl[ci][k][c] = w[((size_t)(c*NC + ci0 + ci))*9 + k];
  }
  float acc[27];
  #pragma unroll
  for (int c = 0; c < 27; ++c) acc[c] = 0.f;
  int ty = t >> 4, tx = t & 15;
  for (int ci = 0; ci < 32; ++ci){
    const float* xc = x + ((size_t)(b*NC + ci0 + ci))*N;
    __syncthreads();
    for (int s = t; s < 324; s += 256){
      int hy = s / 18, hx = s % 18;
      int gy = ty0 + hy - 1, gx = tx0 + hx - 1;
      hl[hy][hx] = (gy >= 0 && gy < H && gx >= 0 && gx < W) ? xc[gy*W + gx] : 0.f;
    }
    __syncthreads();
    float xv[9];
    #pragma unroll
    for (int ky = 0; ky < 3; ++ky)
      #pragma unroll
      for (int kx = 0; kx < 3; ++kx)
        xv[ky*3+kx] = hl[ty+ky][tx+kx];
    #pragma unroll
    for (int k = 0; k < 9; ++k){
      float xk = xv[k];
      #pragma unroll
      for (int c4 = 0; c4 < 6; ++c4){
        float4 wv = *(float4*)&wl[ci][k][c4*4];
        acc[c4*4+0] = fmaf(wv.x, xk, acc[c4*4+0]);
        acc[c4*4+1] = fmaf(wv.y, xk, acc[c4*4+1]);
        acc[c4*4+2] = fmaf(wv.z, xk, acc[c4*4+2]);
        acc[c4*4+3] = fmaf(wv.w, xk, acc[c4*4+3]);
      }
      acc[24] = fmaf(wl[ci][k][24], xk, acc[24]);
      acc[25] = fmaf(wl[ci][k][25], xk, acc[25]);
      acc[26] = fmaf(wl[ci][k][26], xk, acc[26]);
    }
  }
  int hw = (ty0 + ty)*W + (tx0 + tx);
  float* pp = partial + ((size_t)(chunk*NB + b)*27)*N + hw;
  #pragma unroll
  for (int c = 0; c < 27; ++c) pp[(size_t)c*N] = acc[c];
}

__global__ __launch_bounds__(256) void conv_reduce(
    const float* __restrict__ partial, const float* __restrict__ bias,
    float* __restrict__ off, float* __restrict__ mask, int N){
  int idx = blockIdx.x*256 + threadIdx.x;
  int total = NB*27*N;
  if (idx >= total) return;
  int hw = idx % N;
  int c  = (idx / N) % 27;
  int b  = idx / (27*N);
  float s = bias[c];
  #pragma unroll
  for (int p = 0; p < 8; ++p)
    s += partial[((size_t)(p*NB + b)*27 + c)*N + hw];
  if (c < 18) off[((size_t)b*18 + c)*N + hw] = s;
  else        mask[((size_t)b*9 + (c-18))*N + hw] = 1.f/(1.f + expf(-s));
}

// ---------------- align-corners bilinear resize (+optional fused channel pool) ----------------
__global__ __launch_bounds__(256) void resize_pool_kernel(
    const float* __restrict__ in, float* __restrict__ out,
    float* __restrict__ pooled,      // may be null; raw-sum atomic per channel
    int C, int H, int W, int Ho, int Wo){
  __shared__ float buf[256];
  int No = Ho*Wo;
  int idx = blockIdx.x*256 + threadIdx.x;
  int total = NB*C*No;
  float v = 0.f;
  int bc = 0;
  if (idx < total){
    int xo = idx % Wo;
    int yo = (idx / Wo) % Ho;
    bc = idx / No;
    float fy = (float)(H-1) / (float)(Ho-1);
    float fx = (float)(W-1) / (float)(Wo-1);
    float ys = yo * fy, xs = xo * fx;
    int y0 = (int)floorf(ys), x0i = (int)floorf(xs);
    int y1 = min(y0+1, H-1), x1 = min(x0i+1, W-1);
    float wy = ys - (float)y0, wx = xs - (float)x0i;
    const float* p = in + (size_t)bc*H*W;
    float v00 = p[y0*W+x0i], v01 = p[y0*W+x1];
    float v10 = p[y1*W+x0i], v11 = p[y1*W+x1];
    float r0 = v00*(1.f-wy) + v10*wy;
    float r1 = v01*(1.f-wy) + v11*wy;
    v = r0*(1.f-wx) + r1*wx;
    out[idx] = v;
  }
  if (pooled){
    float s = blk_reduce(v, buf);   // No%256==0 -> block within one bc
    if (threadIdx.x == 0) atomicAdd(&pooled[bc], s);
  }
}

// ---------------- deformable sampling -> colsT[b][m/8][hw][m%8] bf16 ----------------
__global__ __launch_bounds__(256) void sample_t_kernel(
    const float* __restrict__ x, const float* __restrict__ off,
    const float* __restrict__ mask, unsigned short* __restrict__ colsT,
    int Hi, int Wi, int Ho, int Wo, int stride){
  int N = Ho*Wo;
  int idx = blockIdx.x*256 + threadIdx.x;
  int total = NB*32*N;
  if (idx >= total) return;
  int hw = idx % N;
  int c8 = (idx / N) & 31;
  int b  = idx / (32*N);
  int yo = hw / Wo, xo = hw % Wo;
  int HiWi = Hi*Wi;
  const float* xb = x + (size_t)(b*NC + c8*8)*HiWi;
  const float* ob = off + (size_t)b*18*N;
  const float* mb = mask + (size_t)b*9*N;
  unsigned short* cb = colsT + (size_t)b*288*N*8;
  float Hm1 = (float)(Hi-1), Wm1 = (float)(Wi-1);
  #pragma unroll
  for (int kp = 0; kp < 9; ++kp){
    int ky = kp/3, kx = kp%3;
    float py = (float)(yo*stride - 1 + ky) + ob[(size_t)(2*kp)*N + hw];
    float px = (float)(xo*stride - 1 + kx) + ob[(size_t)(2*kp+1)*N + hw];
    float m  = mb[(size_t)kp*N + hw];
    float y0f = floorf(py), x0f = floorf(px);
    float wy = py - y0f, wx = px - x0f;
    bool vy0 = (y0f >= 0.f)    && (y0f <= Hm1);
    bool vy1 = (y0f+1.f >= 0.f)&& (y0f+1.f <= Hm1);
    bool vx0 = (x0f >= 0.f)    && (x0f <= Wm1);
    bool vx1 = (x0f+1.f >= 0.f)&& (x0f+1.f <= Wm1);
    int y0i = min(max((int)y0f, 0), Hi-1);
    int y1i = min(max((int)y0f + 1, 0), Hi-1);
    int x0i = min(max((int)x0f, 0), Wi-1);
    int x1i = min(max((int)x0f + 1, 0), Wi-1);
    float w00 = (1.f-wy)*(1.f-wx) * (vy0 && vx0 ? 1.f : 0.f);
    float w01 = (1.f-wy)*wx       * (vy0 && vx1 ? 1.f : 0.f);
    float w10 = wy*(1.f-wx)       * (vy1 && vx0 ? 1.f : 0.f);
    float w11 = wy*wx             * (vy1 && vx1 ? 1.f : 0.f);
    int i00 = y0i*Wi + x0i, i01 = y0i*Wi + x1i;
    int i10 = y1i*Wi + x0i, i11 = y1i*Wi + x1i;
    unsigned int ou[4];
    #pragma unroll
    for (int p = 0; p < 4; ++p){
      const float* xp0 = xb + (size_t)(2*p)*HiWi;
      const float* xp1 = xb + (size_t)(2*p+1)*HiWi;
      float v0 = (w00*xp0[i00] + w01*xp0[i01] + w10*xp0[i10] + w11*xp0[i11]) * m;
      float v1 = (w00*xp1[i00] + w01*xp1[i01] + w10*xp1[i10] + w11*xp1[i11]) * m;
      ou[p] = (unsigned int)bf16r(v0) | ((unsigned int)bf16r(v1) << 16);
    }
    int chunk = kp*32 + c8;
    *(uint4*)(cb + ((size_t)chunk*N + hw)*8) =
        make_uint4(ou[0], ou[1], ou[2], ou[3]);
  }
}

// ---------------- weight re-tile: At[m/8][co][m%8] bf16, m = kp*256+ci ----------------
__global__ __launch_bounds__(256) void wtrans_t_kernel(
    const float* __restrict__ w, unsigned short* __restrict__ At){
  int j = blockIdx.x*256 + threadIdx.x;
  if (j >= 2304*256) return;
  int e = j & 7, co = (j >> 3) & 255, chunk = j >> 11;
  int kp = chunk >> 5, ci = (chunk & 31)*8 + e;
  At[j] = bf16r(w[((size_t)(co*NC + ci))*9 + kp]);
}

// ---------------- MFMA GEMM + fused GN-stats atomics ----------------
// block: 64 hw x 256 co, 4 waves. Output row = wv*64+mi*16+(lg*4+r) -> GN group
// of a (wave,mi) pair is uniform: g = wv*4+mi. stats[(b*16+g)*2 + {0,1}] += {sum, sumsq}.
__global__ __launch_bounds__(256) void gemm_t_kernel(
    const unsigned short* __restrict__ At,
    const unsigned short* __restrict__ colsT,
    float* __restrict__ C, float* __restrict__ stats, int N){
  int b = blockIdx.z;
  int hw0 = blockIdx.x * 64;
  int tid = threadIdx.x;
  int wv = tid >> 6, l = tid & 63;
  int cobase = wv * 64;
  int lr = l & 15, lg = l >> 4;
  const unsigned short* Bb = colsT + (size_t)b*288*N*8;
  f32x4 acc[4][4];
  #pragma unroll
  for (int mi = 0; mi < 4; ++mi)
    #pragma unroll
    for (int ni = 0; ni < 4; ++ni)
      acc[mi][ni] = (f32x4){0.f, 0.f, 0.f, 0.f};
  for (int kc = 0; kc < 288; kc += 4){
    bf16x8 a[4], bfr[4];
    #pragma unroll
    for (int mi = 0; mi < 4; ++mi)
      a[mi] = *(const bf16x8*)(At + ((size_t)(kc+lg)*256 + cobase + mi*16 + lr)*8);
    #pragma unroll
    for (int ni = 0; ni < 4; ++ni)
      bfr[ni] = *(const bf16x8*)(Bb + ((size_t)(kc+lg)*N + hw0 + ni*16 + lr)*8);
    #pragma unroll
    for (int mi = 0; mi < 4; ++mi)
      #pragma unroll
      for (int ni = 0; ni < 4; ++ni)
        acc[mi][ni] = __builtin_amdgcn_mfma_f32_16x16x32_bf16(a[mi], bfr[ni], acc[mi][ni], 0, 0, 0);
  }
  #pragma unroll
  for (int mi = 0; mi < 4; ++mi){
    float s = 0.f, ss = 0.f;
    #pragma unroll
    for (int ni = 0; ni < 4; ++ni)
      #pragma unroll
      for (int r = 0; r < 4; ++r){
        float v = acc[mi][ni][r];
        int row = cobase + mi*16 + lg*4 + r;
        int col = hw0 + ni*16 + lr;
        C[((size_t)b*NC + row)*N + col] = v;
        s += v; ss = fmaf(v, v, ss);
      }
    #pragma unroll
    for (int o = 32; o > 0; o >>= 1){
      s  += __shfl_xor(s,  o);
      ss += __shfl_xor(ss, o);
    }
    if (l == 0){
      int g = b*16 + wv*4 + mi;
      atomicAdd(&stats[g*2],     s);
      atomicAdd(&stats[g*2 + 1], ss);
    }
  }
}

// ---------------- GN apply (elementwise, full grid) + fused channel pool ----------------
__global__ __launch_bounds__(256) void gn_apply_pool(
    float* __restrict__ f, const float* __restrict__ gamma,
    const float* __restrict__ beta, const float* __restrict__ stats,
    float* __restrict__ pooled,      // may be null; raw-sum atomic per channel
    int N, float inv_cnt){
  __shared__ float buf[256];
  int idx = blockIdx.x*256 + threadIdx.x;   // grid exact: NB*NC*N / 256
  int c = (idx / N) & (NC-1);
  int b = idx / (NC*N);
  int g = b*16 + (c >> 4);
  float s_  = stats[g*2];
  float ss_ = stats[g*2 + 1];
  float mu  = s_ * inv_cnt;
  float var = ss_ * inv_cnt - mu*mu;
  float rstd = rsqrtf(var + 1e-5f);
  float v = (f[idx] - mu)*rstd*gamma[c] + beta[c];
  f[idx] = v;
  if (pooled){
    float bs = blk_reduce(v, buf);   // N%256==0 -> block within one (b,c)
    if (threadIdx.x == 0) atomicAdd(&pooled[b*NC + c], bs);
  }
}

// ---------------- scale attention scalar (pooled holds raw sums) ----------------
__global__ __launch_bounds__(256) void attn_kernel(
    const float* __restrict__ pooled, const float* __restrict__ wsc,
    const float* __restrict__ bsc, float* __restrict__ scal, float inv_N){
  __shared__ float buf[256];
  int b = blockIdx.x;
  float v = pooled[b*NC + threadIdx.x] * inv_N * wsc[threadIdx.x];
  float t = blk_reduce(v, buf);
  if (threadIdx.x == 0){
    float z = fmaxf(t + bsc[0], 0.f);
    scal[b] = hsig_(z);
  }
}

// ---------------- weighted combine + fused plsum pool ----------------
__global__ __launch_bounds__(256) void combine_pool_kernel(
    const float* __restrict__ fm, const float* __restrict__ fl,
    const float* __restrict__ fh, const float* __restrict__ scal,
    float* __restrict__ outp, float* __restrict__ plsum,
    int N, float inv_n){
  __shared__ float buf[256];
  int idx = blockIdx.x*256 + threadIdx.x;
  int b = idx / (NC*N);
  int c = (idx / N) & (NC-1);
  float v = fm[idx] * scal[b];
  if (fl) v = fmaf(fl[idx], scal[2+b], v);
  if (fh) v = fmaf(fh[idx], scal[4+b], v);
  v *= inv_n;
  outp[idx] = v;
  float bs = blk_reduce(v, buf);
  if (threadIdx.x == 0) atomicAdd(&plsum[b*NC + c], bs);
}

// ---------------- DyReLU MLP (plsum holds raw sums) ----------------
__global__ __launch_bounds__(256) void dyrelu_mlp_kernel(
    const float* __restrict__ plsum,
    const float* __restrict__ w1, const float* __restrict__ b1,
    const float* __restrict__ w2, const float* __restrict__ b2,
    float* __restrict__ coef, float inv_N){
  __shared__ float pld[256];
  __shared__ float h[64];
  int b = blockIdx.x, t = threadIdx.x;
  pld[t] = plsum[b*NC + t] * inv_N;
  __syncthreads();
  if (t < 64){
    float a = b1[t];
    for(int c=0; c<256; ++c) a = fmaf(w1[t*256 + c], pld[c], a);
    h[t] = fmaxf(a, 0.f);
  }
  __syncthreads();
  for(int q=0; q<4; ++q){
    int o = q*256 + t;
    float a = b2[o];
    #pragma unroll 8
    for(int k=0; k<64; ++k) a = fmaf(w2[o*64 + k], h[k], a);
    coef[b*1024 + o] = hsig_(a) - 0.5f;
  }
}

// ---------------- DyReLU apply ----------------
__global__ __launch_bounds__(256) void dyrelu_apply_kernel(
    const float* __restrict__ sf, const float* __restrict__ coef,
    float* __restrict__ out, int N){
  int idx = blockIdx.x*256 + threadIdx.x;
  int c = (idx / N) & (NC-1);
  int b = idx / (NC*N);
  const float* cf = coef + b*1024;
  float a1 = fmaf(cf[c], 2.f, 1.f);
  float bb1 = cf[256 + c];
  float a2 = cf[512 + c]*2.f;
  float bb2 = cf[768 + c];
  float v = sf[idx];
  out[idx] = fmaxf(fmaf(v, a1, bb1), fmaf(v, a2, bb2));
}

extern "C" void kernel_launch(void* const* d_in, const int* in_sizes, int n_in,
                              void* d_out, int out_size, void* d_ws, size_t ws_size,
                              hipStream_t stream){
  const float* x0      = (const float*)d_in[0];
  const float* x1      = (const float*)d_in[1];
  const float* x2      = (const float*)d_in[2];
  const float* w_off   = (const float*)d_in[3];
  const float* b_off   = (const float*)d_in[4];
  const float* w_mid   = (const float*)d_in[5];
  const float* g_mid   = (const float*)d_in[6];
  const float* bt_mid  = (const float*)d_in[7];
  const float* w_low   = (const float*)d_in[8];
  const float* g_low   = (const float*)d_in[9];
  const float* bt_low  = (const float*)d_in[10];
  const float* w_high  = (const float*)d_in[11];
  const float* g_high  = (const float*)d_in[12];
  const float* bt_high = (const float*)d_in[13];
  const float* w_scale = (const float*)d_in[14];
  const float* b_scale = (const float*)d_in[15];
  const float* w1      = (const float*)d_in[16];
  const float* b1      = (const float*)d_in[17];
  const float* w2      = (const float*)d_in[18];
  const float* b2      = (const float*)d_in[19];
  float* out = (float*)d_out;

  char* wp_ = (char*)d_ws;
  auto alloc = [&](size_t bytes) -> char* {
    char* r = wp_;
    wp_ += (bytes + 255) & ~(size_t)255;
    return r;
  };
  float* off0  = (float*)alloc((size_t)NB*18*4096*4);
  float* off1  = (float*)alloc((size_t)NB*18*1024*4);
  float* off2  = (float*)alloc((size_t)NB*18*256*4);
  float* mask0 = (float*)alloc((size_t)NB*9*4096*4);
  float* mask1 = (float*)alloc((size_t)NB*9*1024*4);
  float* mask2 = (float*)alloc((size_t)NB*9*256*4);
  float* offr  = (float*)alloc((size_t)NB*18*1024*4);
  float* maskr = (float*)alloc((size_t)NB*9*1024*4);
  float* partial = (float*)alloc((size_t)8*NB*27*4096*4);
  unsigned short* Atm = (unsigned short*)alloc((size_t)2304*256*2);
  unsigned short* Atl = (unsigned short*)alloc((size_t)2304*256*2);
  unsigned short* Ath = (unsigned short*)alloc((size_t)2304*256*2);
  unsigned short* colsT = (unsigned short*)alloc((size_t)NB*288*4096*8*2);
  float* fmid  = (float*)alloc((size_t)NB*NC*4096*4);
  float* flow  = (float*)alloc((size_t)NB*NC*4096*4);
  float* fhis  = (float*)alloc((size_t)NB*NC*1024*4);
  float* fhi   = (float*)alloc((size_t)NB*NC*4096*4);
  float* sumf  = (float*)alloc((size_t)NB*NC*4096*4);
  // contiguous small-stats region (zeroed per level): statsm/l/h + 4 pooled bufs
  float* statsm = (float*)alloc((size_t)(64*3 + 512*4)*4);
  float* statsl = statsm + 64;
  float* statsh = statsm + 128;
  float* plmid  = statsm + 192;
  float* pllow  = plmid + 512;
  float* plhi   = plmid + 1024;
  float* plsum  = plmid + 1536;
  const int ZN = 64*3 + 512*4;
  float* scal  = (float*)alloc(8*4);
  float* coef  = (float*)alloc((size_t)NB*1024*4);
  (void)ws_size; (void)in_sizes; (void)n_in; (void)out_size;

  wtrans_t_kernel<<<2304, 256, 0, stream>>>(w_mid, Atm);
  wtrans_t_kernel<<<2304, 256, 0, stream>>>(w_low, Atl);
  wtrans_t_kernel<<<2304, 256, 0, stream>>>(w_high, Ath);

  const int   sizes[3] = {64, 32, 16};
  const float* xs[3]   = {x0, x1, x2};
  float* OFF[3]  = {off0, off1, off2};
  float* MASK[3] = {mask0, mask1, mask2};
  const size_t outoff[3] = {0, (size_t)NB*NC*4096, (size_t)NB*NC*4096 + (size_t)NB*NC*1024};

  for(int l=0; l<3; ++l){
    int H = sizes[l], W = H, N = H*W;
    int totBCN = NB*NC*N;
    int tilesx = H/16;
    float invN = 1.f/(float)N;
    float inv_cnt = 1.f/(float)(16*N);

    zero_kernel<<<(ZN+255)/256, 256, 0, stream>>>(statsm, ZN);

    conv_off_tiled<<<dim3(tilesx*tilesx, 8, NB), 256, 0, stream>>>(
        xs[l], w_off, partial, H, W, tilesx);
    conv_reduce<<<(NB*27*N+255)/256, 256, 0, stream>>>(
        partial, b_off, OFF[l], MASK[l], N);

    // ---- mid ----
    sample_t_kernel<<<(NB*32*N)/256, 256, 0, stream>>>(
        xs[l], OFF[l], MASK[l], colsT, H, W, H, W, 1);
    gemm_t_kernel<<<dim3(N/64, 1, NB), 256, 0, stream>>>(Atm, colsT, fmid, statsm, N);
    gn_apply_pool<<<totBCN/256, 256, 0, stream>>>(fmid, g_mid, bt_mid, statsm, plmid, N, inv_cnt);
    attn_kernel<<<NB, 256, 0, stream>>>(plmid, w_scale, b_scale, scal + 0, invN);

    int nf = 1;
    const float* flowp = nullptr;
    const float* fhip  = nullptr;

    // ---- low (stride-2 from previous, finer level) ----
    if (l > 0){
      int Hp = sizes[l-1];
      sample_t_kernel<<<(NB*32*N)/256, 256, 0, stream>>>(
          xs[l-1], OFF[l], MASK[l], colsT, Hp, Hp, H, W, 2);
      gemm_t_kernel<<<dim3(N/64, 1, NB), 256, 0, stream>>>(Atl, colsT, flow, statsl, N);
      gn_apply_pool<<<totBCN/256, 256, 0, stream>>>(flow, g_low, bt_low, statsl, pllow, N, inv_cnt);
      attn_kernel<<<NB, 256, 0, stream>>>(pllow, w_scale, b_scale, scal + 2, invN);
      nf++; flowp = flow;
    }

    // ---- high (next, coarser level) ----
    if (l < 2){
      int Ht = sizes[l+1], Nt = Ht*Ht;
      float inv_cnt_h = 1.f/(float)(16*Nt);
      resize_pool_kernel<<<(NB*18*Nt+255)/256, 256, 0, stream>>>(OFF[l], offr, nullptr, 18, H, W, Ht, Ht);
      resize_pool_kernel<<<(NB*9*Nt+255)/256, 256, 0, stream>>>(MASK[l], maskr, nullptr, 9, H, W, Ht, Ht);
      sample_t_kernel<<<(NB*32*Nt)/256, 256, 0, stream>>>(
          xs[l+1], offr, maskr, colsT, Ht, Ht, Ht, Ht, 1);
      gemm_t_kernel<<<dim3(Nt/64, 1, NB), 256, 0, stream>>>(Ath, colsT, fhis, statsh, Nt);
      gn_apply_pool<<<(NB*NC*Nt)/256, 256, 0, stream>>>(fhis, g_high, bt_high, statsh, nullptr, Nt, inv_cnt_h);
      resize_pool_kernel<<<totBCN/256, 256, 0, stream>>>(fhis, fhi, plhi, NC, Ht, Ht, H, W);
      attn_kernel<<<NB, 256, 0, stream>>>(plhi, w_scale, b_scale, scal + 4, invN);
      nf++; fhip = fhi;
    }

    // ---- combine + DyReLU ----
    combine_pool_kernel<<<totBCN/256, 256, 0, stream>>>(
        fmid, flowp, fhip, scal, sumf, plsum, N, 1.f/(float)nf);
    dyrelu_mlp_kernel<<<NB, 256, 0, stream>>>(plsum, w1, b1, w2, b2, coef, invN);
    dyrelu_apply_kernel<<<totBCN/256, 256, 0, stream>>>(
        sumf, coef, out + outoff[l], N);
  }
}

// Round 9
// 827.804 us; speedup vs baseline: 2.2190x; 1.2795x over previous
//
#include <hip/hip_runtime.h>
#include <math.h>

// DyHeadBlock forward. B=2, C=256, levels 64x64 / 32x32 / 16x16.
// Round 7: 32x32 wave-tile GEMM (2048 waves, reg prefetch), x transposed to
// [hw][ci] bf16 for coalesced sampling, colsT relayout [kp][hw][ci].

#define NB 2
#define NC 256

typedef __attribute__((ext_vector_type(8))) short bf16x8;
typedef __attribute__((ext_vector_type(4))) float f32x4;

static __device__ __forceinline__ float hsig_(float x){
  return fminf(fmaxf(x + 3.f, 0.f), 6.f) * (1.f/6.f);
}

static __device__ __forceinline__ unsigned short bf16r(float f){
  unsigned int u = __float_as_uint(f);
  unsigned int r = (u + 0x7FFFu + ((u >> 16) & 1u)) >> 16;   // RTNE
  return (unsigned short)r;
}

static __device__ __forceinline__ float bf2f(unsigned short u){
  return __uint_as_float(((unsigned int)u) << 16);
}

static __device__ __forceinline__ float blk_reduce(float v, float* buf){
  int t = threadIdx.x;
  buf[t] = v; __syncthreads();
  for(int s=128; s>0; s>>=1){
    if (t < s) buf[t] += buf[t+s];
    __syncthreads();
  }
  float r = buf[0];
  __syncthreads();
  return r;
}

// ---------------- zero small stats/pool region ----------------
__global__ __launch_bounds__(256) void zero_kernel(float* __restrict__ p, int n){
  int i = blockIdx.x*256 + threadIdx.x;
  if (i < n) p[i] = 0.f;
}

// ---------------- x transpose: x[b][ci][hw] f32 -> xt[b][hw][ci] bf16 ----------------
// block: 64 hw x 32 ci tile. grid: (N/64) * 8 * NB
__global__ __launch_bounds__(256) void xpose_kernel(
    const float* __restrict__ x, unsigned short* __restrict__ xt, int N){
  __shared__ float tile[32][65];
  int t = threadIdx.x;
  int nb = N >> 6;
  int hw0 = (blockIdx.x % nb) * 64;
  int cg8 = (blockIdx.x / nb) & 7;       // ci-group of 32
  int b   = blockIdx.x / (nb*8);
  int ci0 = cg8 * 32;
  const float* xb = x + ((size_t)(b*NC + ci0))*N;
  #pragma unroll
  for (int it = 0; it < 8; ++it){
    int idx = it*256 + t;
    int ci = idx >> 6, hwl = idx & 63;
    tile[ci][hwl] = xb[(size_t)ci*N + hw0 + hwl];
  }
  __syncthreads();
  int hwl = t >> 2, cg = t & 3;
  unsigned int ou[4];
  #pragma unroll
  for (int p = 0; p < 4; ++p){
    unsigned int lo = bf16r(tile[cg*8 + 2*p][hwl]);
    unsigned int hi = bf16r(tile[cg*8 + 2*p + 1][hwl]);
    ou[p] = lo | (hi << 16);
  }
  *(uint4*)(xt + ((size_t)b*N + hw0 + hwl)*256 + ci0 + cg*8) =
      make_uint4(ou[0], ou[1], ou[2], ou[3]);
}

// ---------------- conv_off, tiled ----------------
__global__ __launch_bounds__(256) void conv_off_tiled(
    const float* __restrict__ x, const float* __restrict__ w,
    float* __restrict__ partial, int H, int W, int tilesx){
  __shared__ float hl[18][20];
  __shared__ float wl[32][9][28];
  int b = blockIdx.z, chunk = blockIdx.y;
  int ty0 = (blockIdx.x / tilesx) * 16, tx0 = (blockIdx.x % tilesx) * 16;
  int t = threadIdx.x;
  int ci0 = chunk * 32;
  int N = H * W;
  for (int s = t; s < 27*32*9; s += 256){
    int c = s / 288, rem = s % 288, ci = rem / 9, k = rem % 9;
    wl[ci][k][c] = w[((size_t)(c*NC + ci0 + ci))*9 + k];
  }
  float acc[27];
  #pragma unroll
  for (int c = 0; c < 27; ++c) acc[c] = 0.f;
  int ty = t >> 4, tx = t & 15;
  for (int ci = 0; ci < 32; ++ci){
    const float* xc = x + ((size_t)(b*NC + ci0 + ci))*N;
    __syncthreads();
    for (int s = t; s < 324; s += 256){
      int hy = s / 18, hx = s % 18;
      int gy = ty0 + hy - 1, gx = tx0 + hx - 1;
      hl[hy][hx] = (gy >= 0 && gy < H && gx >= 0 && gx < W) ? xc[gy*W + gx] : 0.f;
    }
    __syncthreads();
    float xv[9];
    #pragma unroll
    for (int ky = 0; ky < 3; ++ky)
      #pragma unroll
      for (int kx = 0; kx < 3; ++kx)
        xv[ky*3+kx] = hl[ty+ky][tx+kx];
    #pragma unroll
    for (int k = 0; k < 9; ++k){
      float xk = xv[k];
      #pragma unroll
      for (int c4 = 0; c4 < 6; ++c4){
        float4 wv = *(float4*)&wl[ci][k][c4*4];
        acc[c4*4+0] = fmaf(wv.x, xk, acc[c4*4+0]);
        acc[c4*4+1] = fmaf(wv.y, xk, acc[c4*4+1]);
        acc[c4*4+2] = fmaf(wv.z, xk, acc[c4*4+2]);
        acc[c4*4+3] = fmaf(wv.w, xk, acc[c4*4+3]);
      }
      acc[24] = fmaf(wl[ci][k][24], xk, acc[24]);
      acc[25] = fmaf(wl[ci][k][25], xk, acc[25]);
      acc[26] = fmaf(wl[ci][k][26], xk, acc[26]);
    }
  }
  int hw = (ty0 + ty)*W + (tx0 + tx);
  float* pp = partial + ((size_t)(chunk*NB + b)*27)*N + hw;
  #pragma unroll
  for (int c = 0; c < 27; ++c) pp[(size_t)c*N] = acc[c];
}

__global__ __launch_bounds__(256) void conv_reduce(
    const float* __restrict__ partial, const float* __restrict__ bias,
    float* __restrict__ off, float* __restrict__ mask, int N){
  int idx = blockIdx.x*256 + threadIdx.x;
  int total = NB*27*N;
  if (idx >= total) return;
  int hw = idx % N;
  int c  = (idx / N) % 27;
  int b  = idx / (27*N);
  float s = bias[c];
  #pragma unroll
  for (int p = 0; p < 8; ++p)
    s += partial[((size_t)(p*NB + b)*27 + c)*N + hw];
  if (c < 18) off[((size_t)b*18 + c)*N + hw] = s;
  else        mask[((size_t)b*9 + (c-18))*N + hw] = 1.f/(1.f + expf(-s));
}

// ---------------- align-corners bilinear resize (+optional fused channel pool) ----------------
__global__ __launch_bounds__(256) void resize_pool_kernel(
    const float* __restrict__ in, float* __restrict__ out,
    float* __restrict__ pooled, int C, int H, int W, int Ho, int Wo){
  __shared__ float buf[256];
  int No = Ho*Wo;
  int idx = blockIdx.x*256 + threadIdx.x;
  int total = NB*C*No;
  float v = 0.f;
  int bc = 0;
  if (idx < total){
    int xo = idx % Wo;
    int yo = (idx / Wo) % Ho;
    bc = idx / No;
    float fy = (float)(H-1) / (float)(Ho-1);
    float fx = (float)(W-1) / (float)(Wo-1);
    float ys = yo * fy, xs = xo * fx;
    int y0 = (int)floorf(ys), x0i = (int)floorf(xs);
    int y1 = min(y0+1, H-1), x1 = min(x0i+1, W-1);
    float wy = ys - (float)y0, wx = xs - (float)x0i;
    const float* p = in + (size_t)bc*H*W;
    float v00 = p[y0*W+x0i], v01 = p[y0*W+x1];
    float v10 = p[y1*W+x0i], v11 = p[y1*W+x1];
    float r0 = v00*(1.f-wy) + v10*wy;
    float r1 = v01*(1.f-wy) + v11*wy;
    v = r0*(1.f-wx) + r1*wx;
    out[idx] = v;
  }
  if (pooled){
    float s = blk_reduce(v, buf);
    if (threadIdx.x == 0) atomicAdd(&pooled[bc], s);
  }
}

// ---------------- deformable sampling from xt -> cols[b][kp][hw][ci] bf16 ----------------
// block: 8 hw x 32 c8 (c8 fastest). Corner loads: 32 lanes same hw -> 512B contiguous.
__global__ __launch_bounds__(256) void sample_t2_kernel(
    const unsigned short* __restrict__ xt, const float* __restrict__ off,
    const float* __restrict__ mask, unsigned short* __restrict__ cols,
    int Hi, int Wi, int Ho, int Wo, int stride){
  int N = Ho*Wo;
  int t = threadIdx.x;
  int c8 = t & 31, hw_l = t >> 5;
  int nb = N >> 3;
  int b  = blockIdx.x / nb;
  int hw = (blockIdx.x % nb)*8 + hw_l;
  int yo = hw / Wo, xo = hw % Wo;
  int HiWi = Hi*Wi;
  const unsigned short* xb = xt + (size_t)b*HiWi*256 + c8*8;
  const float* ob = off + (size_t)b*18*N;
  const float* mb = mask + (size_t)b*9*N;
  unsigned short* cb = cols + (size_t)b*9*N*256;
  float Hm1 = (float)(Hi-1), Wm1 = (float)(Wi-1);
  #pragma unroll
  for (int kp = 0; kp < 9; ++kp){
    int ky = kp/3, kx = kp%3;
    float py = (float)(yo*stride - 1 + ky) + ob[(size_t)(2*kp)*N + hw];
    float px = (float)(xo*stride - 1 + kx) + ob[(size_t)(2*kp+1)*N + hw];
    float m  = mb[(size_t)kp*N + hw];
    float y0f = floorf(py), x0f = floorf(px);
    float wy = py - y0f, wx = px - x0f;
    bool vy0 = (y0f >= 0.f)     && (y0f <= Hm1);
    bool vy1 = (y0f+1.f >= 0.f) && (y0f+1.f <= Hm1);
    bool vx0 = (x0f >= 0.f)     && (x0f <= Wm1);
    bool vx1 = (x0f+1.f >= 0.f) && (x0f+1.f <= Wm1);
    int y0i = min(max((int)y0f, 0), Hi-1);
    int y1i = min(max((int)y0f + 1, 0), Hi-1);
    int x0i = min(max((int)x0f, 0), Wi-1);
    int x1i = min(max((int)x0f + 1, 0), Wi-1);
    float w00 = (1.f-wy)*(1.f-wx) * (vy0 && vx0 ? 1.f : 0.f);
    float w01 = (1.f-wy)*wx       * (vy0 && vx1 ? 1.f : 0.f);
    float w10 = wy*(1.f-wx)       * (vy1 && vx0 ? 1.f : 0.f);
    float w11 = wy*wx             * (vy1 && vx1 ? 1.f : 0.f);
    const bf16x8 c00 = *(const bf16x8*)(xb + (size_t)(y0i*Wi + x0i)*256);
    const bf16x8 c01 = *(const bf16x8*)(xb + (size_t)(y0i*Wi + x1i)*256);
    const bf16x8 c10 = *(const bf16x8*)(xb + (size_t)(y1i*Wi + x0i)*256);
    const bf16x8 c11 = *(const bf16x8*)(xb + (size_t)(y1i*Wi + x1i)*256);
    unsigned int ou[4];
    #pragma unroll
    for (int p = 0; p < 4; ++p){
      float v0 = (w00*bf2f((unsigned short)c00[2*p])   + w01*bf2f((unsigned short)c01[2*p]) +
                  w10*bf2f((unsigned short)c10[2*p])   + w11*bf2f((unsigned short)c11[2*p])) * m;
      float v1 = (w00*bf2f((unsigned short)c00[2*p+1]) + w01*bf2f((unsigned short)c01[2*p+1]) +
                  w10*bf2f((unsigned short)c10[2*p+1]) + w11*bf2f((unsigned short)c11[2*p+1])) * m;
      ou[p] = (unsigned int)bf16r(v0) | ((unsigned int)bf16r(v1) << 16);
    }
    *(uint4*)(cb + ((size_t)kp*N + hw)*256 + c8*8) =
        make_uint4(ou[0], ou[1], ou[2], ou[3]);
  }
}

// ---------------- weight re-tile: At[chunk][co][8] bf16, chunk=kp*32+c8, m=kp*256+c8*8+e ----------------
__global__ __launch_bounds__(256) void wtrans_t_kernel(
    const float* __restrict__ w, unsigned short* __restrict__ At){
  int j = blockIdx.x*256 + threadIdx.x;
  if (j >= 2304*256) return;
  int e = j & 7, co = (j >> 3) & 255, chunk = j >> 11;
  int kp = chunk >> 5, ci = (chunk & 31)*8 + e;
  At[j] = bf16r(w[((size_t)(co*NC + ci))*9 + kp]);
}

// ---------------- MFMA GEMM, 32x32 per wave, reg prefetch, fused GN stats ----------------
// grid: (N/64, 4, NB), block 256 = 4 waves (2co x 2hw of 32x32 tiles).
__global__ __launch_bounds__(256, 2) void gemm_t2_kernel(
    const unsigned short* __restrict__ At,
    const unsigned short* __restrict__ cols,
    float* __restrict__ C, float* __restrict__ stats, int N){
  int b = blockIdx.z;
  int tid = threadIdx.x;
  int wv = tid >> 6, l = tid & 63;
  int wc = wv & 1, wh = wv >> 1;
  int co0 = blockIdx.y*64 + wc*32;
  int hw0 = blockIdx.x*64 + wh*32;
  int lr = l & 15, lg = l >> 4;
  const unsigned short* Bb = cols + (size_t)b*9*N*256;
  f32x4 acc[2][2];
  #pragma unroll
  for (int mi = 0; mi < 2; ++mi)
    #pragma unroll
    for (int ni = 0; ni < 2; ++ni)
      acc[mi][ni] = (f32x4){0.f, 0.f, 0.f, 0.f};

  // per-lane A/B base offsets; chunk index cidx = kc + lg
  #define A_OFF(cidx, mi) (((size_t)(cidx)*256 + co0 + (mi)*16 + lr)*8)
  #define B_OFF(cidx, ni) (((size_t)((cidx) >> 5)*N + hw0 + (ni)*16 + lr)*256 + ((cidx) & 31)*8)

  int c0 = lg;
  bf16x8 a0 = *(const bf16x8*)(At + A_OFF(c0, 0));
  bf16x8 a1 = *(const bf16x8*)(At + A_OFF(c0, 1));
  bf16x8 b0 = *(const bf16x8*)(Bb + B_OFF(c0, 0));
  bf16x8 b1 = *(const bf16x8*)(Bb + B_OFF(c0, 1));
  for (int kc = 0; kc < 284; kc += 4){
    int cn = kc + 4 + lg;
    bf16x8 na0 = *(const bf16x8*)(At + A_OFF(cn, 0));
    bf16x8 na1 = *(const bf16x8*)(At + A_OFF(cn, 1));
    bf16x8 nb0 = *(const bf16x8*)(Bb + B_OFF(cn, 0));
    bf16x8 nb1 = *(const bf16x8*)(Bb + B_OFF(cn, 1));
    acc[0][0] = __builtin_amdgcn_mfma_f32_16x16x32_bf16(a0, b0, acc[0][0], 0, 0, 0);
    acc[0][1] = __builtin_amdgcn_mfma_f32_16x16x32_bf16(a0, b1, acc[0][1], 0, 0, 0);
    acc[1][0] = __builtin_amdgcn_mfma_f32_16x16x32_bf16(a1, b0, acc[1][0], 0, 0, 0);
    acc[1][1] = __builtin_amdgcn_mfma_f32_16x16x32_bf16(a1, b1, acc[1][1], 0, 0, 0);
    a0 = na0; a1 = na1; b0 = nb0; b1 = nb1;
  }
  acc[0][0] = __builtin_amdgcn_mfma_f32_16x16x32_bf16(a0, b0, acc[0][0], 0, 0, 0);
  acc[0][1] = __builtin_amdgcn_mfma_f32_16x16x32_bf16(a0, b1, acc[0][1], 0, 0, 0);
  acc[1][0] = __builtin_amdgcn_mfma_f32_16x16x32_bf16(a1, b0, acc[1][0], 0, 0, 0);
  acc[1][1] = __builtin_amdgcn_mfma_f32_16x16x32_bf16(a1, b1, acc[1][1], 0, 0, 0);
  #undef A_OFF
  #undef B_OFF

  #pragma unroll
  for (int mi = 0; mi < 2; ++mi){
    float s = 0.f, ss = 0.f;
    #pragma unroll
    for (int ni = 0; ni < 2; ++ni)
      #pragma unroll
      for (int r = 0; r < 4; ++r){
        float v = acc[mi][ni][r];
        int row = co0 + mi*16 + lg*4 + r;
        int col = hw0 + ni*16 + lr;
        C[((size_t)b*NC + row)*N + col] = v;
        s += v; ss = fmaf(v, v, ss);
      }
    #pragma unroll
    for (int o = 32; o > 0; o >>= 1){
      s  += __shfl_xor(s,  o);
      ss += __shfl_xor(ss, o);
    }
    if (l == 0){
      int g = b*16 + ((co0 >> 4) + mi);
      atomicAdd(&stats[g*2],     s);
      atomicAdd(&stats[g*2 + 1], ss);
    }
  }
}

// ---------------- GN apply + fused channel pool ----------------
__global__ __launch_bounds__(256) void gn_apply_pool(
    float* __restrict__ f, const float* __restrict__ gamma,
    const float* __restrict__ beta, const float* __restrict__ stats,
    float* __restrict__ pooled, int N, float inv_cnt){
  __shared__ float buf[256];
  int idx = blockIdx.x*256 + threadIdx.x;
  int c = (idx / N) & (NC-1);
  int b = idx / (NC*N);
  int g = b*16 + (c >> 4);
  float s_  = stats[g*2];
  float ss_ = stats[g*2 + 1];
  float mu  = s_ * inv_cnt;
  float var = ss_ * inv_cnt - mu*mu;
  float rstd = rsqrtf(var + 1e-5f);
  float v = (f[idx] - mu)*rstd*gamma[c] + beta[c];
  f[idx] = v;
  if (pooled){
    float bs = blk_reduce(v, buf);
    if (threadIdx.x == 0) atomicAdd(&pooled[b*NC + c], bs);
  }
}

// ---------------- scale attention scalar ----------------
__global__ __launch_bounds__(256) void attn_kernel(
    const float* __restrict__ pooled, const float* __restrict__ wsc,
    const float* __restrict__ bsc, float* __restrict__ scal, float inv_N){
  __shared__ float buf[256];
  int b = blockIdx.x;
  float v = pooled[b*NC + threadIdx.x] * inv_N * wsc[threadIdx.x];
  float t = blk_reduce(v, buf);
  if (threadIdx.x == 0){
    float z = fmaxf(t + bsc[0], 0.f);
    scal[b] = hsig_(z);
  }
}

// ---------------- weighted combine + fused plsum pool ----------------
__global__ __launch_bounds__(256) void combine_pool_kernel(
    const float* __restrict__ fm, const float* __restrict__ fl,
    const float* __restrict__ fh, const float* __restrict__ scal,
    float* __restrict__ outp, float* __restrict__ plsum,
    int N, float inv_n){
  __shared__ float buf[256];
  int idx = blockIdx.x*256 + threadIdx.x;
  int b = idx / (NC*N);
  int c = (idx / N) & (NC-1);
  float v = fm[idx] * scal[b];
  if (fl) v = fmaf(fl[idx], scal[2+b], v);
  if (fh) v = fmaf(fh[idx], scal[4+b], v);
  v *= inv_n;
  outp[idx] = v;
  float bs = blk_reduce(v, buf);
  if (threadIdx.x == 0) atomicAdd(&plsum[b*NC + c], bs);
}

// ---------------- DyReLU MLP ----------------
__global__ __launch_bounds__(256) void dyrelu_mlp_kernel(
    const float* __restrict__ plsum,
    const float* __restrict__ w1, const float* __restrict__ b1,
    const float* __restrict__ w2, const float* __restrict__ b2,
    float* __restrict__ coef, float inv_N){
  __shared__ float pld[256];
  __shared__ float h[64];
  int b = blockIdx.x, t = threadIdx.x;
  pld[t] = plsum[b*NC + t] * inv_N;
  __syncthreads();
  if (t < 64){
    float a = b1[t];
    for(int c=0; c<256; ++c) a = fmaf(w1[t*256 + c], pld[c], a);
    h[t] = fmaxf(a, 0.f);
  }
  __syncthreads();
  for(int q=0; q<4; ++q){
    int o = q*256 + t;
    float a = b2[o];
    #pragma unroll 8
    for(int k=0; k<64; ++k) a = fmaf(w2[o*64 + k], h[k], a);
    coef[b*1024 + o] = hsig_(a) - 0.5f;
  }
}

// ---------------- DyReLU apply ----------------
__global__ __launch_bounds__(256) void dyrelu_apply_kernel(
    const float* __restrict__ sf, const float* __restrict__ coef,
    float* __restrict__ out, int N){
  int idx = blockIdx.x*256 + threadIdx.x;
  int c = (idx / N) & (NC-1);
  int b = idx / (NC*N);
  const float* cf = coef + b*1024;
  float a1 = fmaf(cf[c], 2.f, 1.f);
  float bb1 = cf[256 + c];
  float a2 = cf[512 + c]*2.f;
  float bb2 = cf[768 + c];
  float v = sf[idx];
  out[idx] = fmaxf(fmaf(v, a1, bb1), fmaf(v, a2, bb2));
}

extern "C" void kernel_launch(void* const* d_in, const int* in_sizes, int n_in,
                              void* d_out, int out_size, void* d_ws, size_t ws_size,
                              hipStream_t stream){
  const float* x0      = (const float*)d_in[0];
  const float* x1      = (const float*)d_in[1];
  const float* x2      = (const float*)d_in[2];
  const float* w_off   = (const float*)d_in[3];
  const float* b_off   = (const float*)d_in[4];
  const float* w_mid   = (const float*)d_in[5];
  const float* g_mid   = (const float*)d_in[6];
  const float* bt_mid  = (const float*)d_in[7];
  const float* w_low   = (const float*)d_in[8];
  const float* g_low   = (const float*)d_in[9];
  const float* bt_low  = (const float*)d_in[10];
  const float* w_high  = (const float*)d_in[11];
  const float* g_high  = (const float*)d_in[12];
  const float* bt_high = (const float*)d_in[13];
  const float* w_scale = (const float*)d_in[14];
  const float* b_scale = (const float*)d_in[15];
  const float* w1      = (const float*)d_in[16];
  const float* b1      = (const float*)d_in[17];
  const float* w2      = (const float*)d_in[18];
  const float* b2      = (const float*)d_in[19];
  float* out = (float*)d_out;

  char* wp_ = (char*)d_ws;
  auto alloc = [&](size_t bytes) -> char* {
    char* r = wp_;
    wp_ += (bytes + 255) & ~(size_t)255;
    return r;
  };
  float* off0  = (float*)alloc((size_t)NB*18*4096*4);
  float* off1  = (float*)alloc((size_t)NB*18*1024*4);
  float* off2  = (float*)alloc((size_t)NB*18*256*4);
  float* mask0 = (float*)alloc((size_t)NB*9*4096*4);
  float* mask1 = (float*)alloc((size_t)NB*9*1024*4);
  float* mask2 = (float*)alloc((size_t)NB*9*256*4);
  float* offr  = (float*)alloc((size_t)NB*18*1024*4);
  float* maskr = (float*)alloc((size_t)NB*9*1024*4);
  float* partial = (float*)alloc((size_t)8*NB*27*4096*4);
  unsigned short* Atm = (unsigned short*)alloc((size_t)2304*256*2);
  unsigned short* Atl = (unsigned short*)alloc((size_t)2304*256*2);
  unsigned short* Ath = (unsigned short*)alloc((size_t)2304*256*2);
  unsigned short* xt0 = (unsigned short*)alloc((size_t)NB*4096*256*2);
  unsigned short* xt1 = (unsigned short*)alloc((size_t)NB*1024*256*2);
  unsigned short* xt2 = (unsigned short*)alloc((size_t)NB*256*256*2);
  unsigned short* colsT = (unsigned short*)alloc((size_t)NB*9*4096*256*2);
  float* fmid  = (float*)alloc((size_t)NB*NC*4096*4);
  float* flow  = (float*)alloc((size_t)NB*NC*4096*4);
  float* fhis  = (float*)alloc((size_t)NB*NC*1024*4);
  float* fhi   = (float*)alloc((size_t)NB*NC*4096*4);
  float* sumf  = (float*)alloc((size_t)NB*NC*4096*4);
  float* statsm = (float*)alloc((size_t)(64*3 + 512*4)*4);
  float* statsl = statsm + 64;
  float* statsh = statsm + 128;
  float* plmid  = statsm + 192;
  float* pllow  = plmid + 512;
  float* plhi   = plmid + 1024;
  float* plsum  = plmid + 1536;
  const int ZN = 64*3 + 512*4;
  float* scal  = (float*)alloc(8*4);
  float* coef  = (float*)alloc((size_t)NB*1024*4);
  (void)ws_size; (void)in_sizes; (void)n_in; (void)out_size;

  wtrans_t_kernel<<<2304, 256, 0, stream>>>(w_mid, Atm);
  wtrans_t_kernel<<<2304, 256, 0, stream>>>(w_low, Atl);
  wtrans_t_kernel<<<2304, 256, 0, stream>>>(w_high, Ath);
  xpose_kernel<<<NB*8*(4096/64), 256, 0, stream>>>(x0, xt0, 4096);
  xpose_kernel<<<NB*8*(1024/64), 256, 0, stream>>>(x1, xt1, 1024);
  xpose_kernel<<<NB*8*(256/64),  256, 0, stream>>>(x2, xt2, 256);

  const int   sizes[3] = {64, 32, 16};
  const float* xs[3]   = {x0, x1, x2};
  const unsigned short* xts[3] = {xt0, xt1, xt2};
  float* OFF[3]  = {off0, off1, off2};
  float* MASK[3] = {mask0, mask1, mask2};
  const size_t outoff[3] = {0, (size_t)NB*NC*4096, (size_t)NB*NC*4096 + (size_t)NB*NC*1024};

  for(int l=0; l<3; ++l){
    int H = sizes[l], W = H, N = H*W;
    int totBCN = NB*NC*N;
    int tilesx = H/16;
    float invN = 1.f/(float)N;
    float inv_cnt = 1.f/(float)(16*N);

    zero_kernel<<<(ZN+255)/256, 256, 0, stream>>>(statsm, ZN);

    conv_off_tiled<<<dim3(tilesx*tilesx, 8, NB), 256, 0, stream>>>(
        xs[l], w_off, partial, H, W, tilesx);
    conv_reduce<<<(NB*27*N+255)/256, 256, 0, stream>>>(
        partial, b_off, OFF[l], MASK[l], N);

    // ---- mid ----
    sample_t2_kernel<<<NB*(N/8), 256, 0, stream>>>(
        xts[l], OFF[l], MASK[l], colsT, H, W, H, W, 1);
    gemm_t2_kernel<<<dim3(N/64, 4, NB), 256, 0, stream>>>(Atm, colsT, fmid, statsm, N);
    gn_apply_pool<<<totBCN/256, 256, 0, stream>>>(fmid, g_mid, bt_mid, statsm, plmid, N, inv_cnt);
    attn_kernel<<<NB, 256, 0, stream>>>(plmid, w_scale, b_scale, scal + 0, invN);

    int nf = 1;
    const float* flowp = nullptr;
    const float* fhip  = nullptr;

    // ---- low (stride-2 from previous, finer level) ----
    if (l > 0){
      int Hp = sizes[l-1];
      sample_t2_kernel<<<NB*(N/8), 256, 0, stream>>>(
          xts[l-1], OFF[l], MASK[l], colsT, Hp, Hp, H, W, 2);
      gemm_t2_kernel<<<dim3(N/64, 4, NB), 256, 0, stream>>>(Atl, colsT, flow, statsl, N);
      gn_apply_pool<<<totBCN/256, 256, 0, stream>>>(flow, g_low, bt_low, statsl, pllow, N, inv_cnt);
      attn_kernel<<<NB, 256, 0, stream>>>(pllow, w_scale, b_scale, scal + 2, invN);
      nf++; flowp = flow;
    }

    // ---- high (next, coarser level) ----
    if (l < 2){
      int Ht = sizes[l+1], Nt = Ht*Ht;
      float inv_cnt_h = 1.f/(float)(16*Nt);
      resize_pool_kernel<<<(NB*18*Nt+255)/256, 256, 0, stream>>>(OFF[l], offr, nullptr, 18, H, W, Ht, Ht);
      resize_pool_kernel<<<(NB*9*Nt+255)/256, 256, 0, stream>>>(MASK[l], maskr, nullptr, 9, H, W, Ht, Ht);
      sample_t2_kernel<<<NB*(Nt/8), 256, 0, stream>>>(
          xts[l+1], offr, maskr, colsT, Ht, Ht, Ht, Ht, 1);
      gemm_t2_kernel<<<dim3(Nt/64, 4, NB), 256, 0, stream>>>(Ath, colsT, fhis, statsh, Nt);
      gn_apply_pool<<<(NB*NC*Nt)/256, 256, 0, stream>>>(fhis, g_high, bt_high, statsh, nullptr, Nt, inv_cnt_h);
      resize_pool_kernel<<<totBCN/256, 256, 0, stream>>>(fhis, fhi, plhi, NC, Ht, Ht, H, W);
      attn_kernel<<<NB, 256, 0, stream>>>(plhi, w_scale, b_scale, scal + 4, invN);
      nf++; fhip = fhi;
    }

    // ---- combine + DyReLU ----
    combine_pool_kernel<<<totBCN/256, 256, 0, stream>>>(
        fmid, flowp, fhip, scal, sumf, plsum, N, 1.f/(float)nf);
    dyrelu_mlp_kernel<<<NB, 256, 0, stream>>>(plsum, w1, b1, w2, b2, coef, invN);
    dyrelu_apply_kernel<<<totBCN/256, 256, 0, stream>>>(
        sumf, coef, out + outoff[l], N);
  }
}